// Round 5
// baseline (120.674 us; speedup 1.0000x reference)
//
#include <hip/hip_runtime.h>
#include <hip/hip_bf16.h>

typedef __bf16 bf16_t;
typedef __bf16 bf16x8 __attribute__((ext_vector_type(8)));
typedef __bf16 bf16x4 __attribute__((ext_vector_type(4)));
typedef float f32x4 __attribute__((ext_vector_type(4)));
typedef unsigned int u32;

#define D_MODEL 1024
#define T_SEQ   2048
#define N_HEADS 16

#define WAITVM(N) asm volatile("s_waitcnt vmcnt(" #N ")" ::: "memory")

__device__ __forceinline__ void gload_lds16(const void* g, void* l) {
  __builtin_amdgcn_global_load_lds((const __attribute__((address_space(1))) u32*)g,
                                   (__attribute__((address_space(3))) u32*)l, 16, 0, 0);
}

__device__ __forceinline__ float fast_exp2(float x) {
#if __has_builtin(__builtin_amdgcn_exp2f)
  return __builtin_amdgcn_exp2f(x);
#else
  return __expf(x * 0.69314718056f);
#endif
}

// ---------------- fused fp32->bf16 cast (x + 4 weights) ----------------
struct CastArgs { const float* src[5]; bf16_t* dst[5]; };

__global__ __launch_bounds__(256) void cast_all(CastArgs p) {
  unsigned i = (blockIdx.x * 256u + threadIdx.x) * 4u;
  int seg; unsigned off;
  if (i < 4194304u) { seg = 0; off = i; }
  else { unsigned r = i - 4194304u; seg = 1 + (int)(r >> 20); off = r & 1048575u; }
  const float4 v = *(const float4*)(p.src[seg] + off);
  bf16x4 o = { (bf16_t)v.x, (bf16_t)v.y, (bf16_t)v.z, (bf16_t)v.w };
  *(bf16x4*)(p.dst[seg] + off) = o;
}

// ---------------- 128x128 bf16 GEMM tile, C = A @ W^T (double-buffered) ----
__device__ __forceinline__ void gemm_stage(
    const bf16_t* __restrict__ A, const bf16_t* __restrict__ W,
    bf16_t* Ad, bf16_t* Bd, int brow, int bcol, int k0, int w, int l) {
  const int srow = l >> 2;
  const int scol = ((l & 3) ^ ((l >> 3) & 3)) * 8;
#pragma unroll
  for (int i = 0; i < 2; ++i) {
    int c = w * 2 + i;
    gload_lds16(A + (size_t)(brow + c * 16 + srow) * D_MODEL + k0 + scol, Ad + c * 512);
    gload_lds16(W + (size_t)(bcol + c * 16 + srow) * D_MODEL + k0 + scol, Bd + c * 512);
  }
}

__device__ __forceinline__ void gemm_tile_128(
    const bf16_t* __restrict__ A, const bf16_t* __restrict__ W,
    bf16_t* Als, bf16_t* Bls, int brow, int bcol, f32x4 acc[4][4])
{
  const int tid = threadIdx.x;
  const int l = tid & 63, w = tid >> 6;
  const int wr = (w >> 1) * 64, wc = (w & 1) * 64;
  const int lh = l >> 4, r15 = l & 15;

  gemm_stage(A, W, Als, Bls, brow, bcol, 0, w, l);

  for (int k0 = 0; k0 < D_MODEL; k0 += 32) {
    const int buf = (k0 >> 5) & 1;
    bf16_t* Ab = Als + buf * 4096;
    bf16_t* Bb = Bls + buf * 4096;
    if (k0 + 32 < D_MODEL) {
      gemm_stage(A, W, Als + (buf ^ 1) * 4096, Bls + (buf ^ 1) * 4096,
                 brow, bcol, k0 + 32, w, l);
      WAITVM(4);
    } else {
      WAITVM(0);
    }
    __builtin_amdgcn_s_barrier();

    bf16x8 af[4], bfr[4];
#pragma unroll
    for (int mi = 0; mi < 4; ++mi) {
      int rr = wr + mi * 16 + r15;
      int s = lh ^ ((rr >> 1) & 3);
      af[mi] = *(const bf16x8*)(Ab + rr * 32 + s * 8);
    }
#pragma unroll
    for (int ni = 0; ni < 4; ++ni) {
      int rr = wc + ni * 16 + r15;
      int s = lh ^ ((rr >> 1) & 3);
      bfr[ni] = *(const bf16x8*)(Bb + rr * 32 + s * 8);
    }
#pragma unroll
    for (int mi = 0; mi < 4; ++mi)
#pragma unroll
      for (int ni = 0; ni < 4; ++ni)
        acc[mi][ni] = __builtin_amdgcn_mfma_f32_16x16x32_bf16(af[mi], bfr[ni], acc[mi][ni], 0, 0, 0);
    __builtin_amdgcn_s_barrier();
  }
}

// ---------------- QKV projection: grid (32, 8, 3) ----------------
// z==0 (Q): output pre-scaled by 0.125*log2(e) so attention uses raw exp2.
// z==2 (V): written TRANSPOSED vt[b][dcol][t].
struct QKVArgs {
  const bf16_t* A;
  const bf16_t* W[3];
  const float* bias[3];
  bf16_t* out[3];
};

#define QSCL 0.18033688011112042f   // 0.125 * log2(e)

__global__ __launch_bounds__(256) void qkv_gemm(QKVArgs p) {
  __shared__ bf16_t Als[2 * 128 * 32], Bls[2 * 128 * 32];
  f32x4 acc[4][4];
  f32x4 zero = {0.f, 0.f, 0.f, 0.f};
#pragma unroll
  for (int i = 0; i < 4; ++i)
#pragma unroll
    for (int j = 0; j < 4; ++j) acc[i][j] = zero;

  const int z = blockIdx.z;
  const int brow = blockIdx.x * 128, bcol = blockIdx.y * 128;
  gemm_tile_128(p.A, p.W[z], Als, Bls, brow, bcol, acc);

  const int tid = threadIdx.x, l = tid & 63, w = tid >> 6;
  const int wr = (w >> 1) * 64, wc = (w & 1) * 64, lh = l >> 4, r15 = l & 15;
  const float* bias = p.bias[z];
  bf16_t* O = p.out[z];

  if (z == 2) {
#pragma unroll
    for (int ni = 0; ni < 4; ++ni) {
      int col = bcol + wc + ni * 16 + r15;
      float bz = bias[col];
#pragma unroll
      for (int mi = 0; mi < 4; ++mi) {
        int row0 = brow + wr + mi * 16 + lh * 4;
        int bb = row0 >> 11, t0 = row0 & 2047;
        bf16x4 pk;
#pragma unroll
        for (int j = 0; j < 4; ++j) pk[j] = (bf16_t)(acc[mi][ni][j] + bz);
        *(bf16x4*)(O + (size_t)bb * (D_MODEL * T_SEQ) + (size_t)col * T_SEQ + t0) = pk;
      }
    }
  } else if (z == 0) {
#pragma unroll
    for (int ni = 0; ni < 4; ++ni) {
      int col = bcol + wc + ni * 16 + r15;
      float bz = bias[col];
#pragma unroll
      for (int mi = 0; mi < 4; ++mi) {
        int row0 = brow + wr + mi * 16 + lh * 4;
#pragma unroll
        for (int j = 0; j < 4; ++j)
          O[(size_t)(row0 + j) * D_MODEL + col] = (bf16_t)((acc[mi][ni][j] + bz) * QSCL);
      }
    }
  } else {
#pragma unroll
    for (int ni = 0; ni < 4; ++ni) {
      int col = bcol + wc + ni * 16 + r15;
      float bz = bias[col];
#pragma unroll
      for (int mi = 0; mi < 4; ++mi) {
        int row0 = brow + wr + mi * 16 + lh * 4;
#pragma unroll
        for (int j = 0; j < 4; ++j)
          O[(size_t)(row0 + j) * D_MODEL + col] = (bf16_t)(acc[mi][ni][j] + bz);
      }
    }
  }
}

// ---------------- output projection: fp32 epilogue ----------------
__global__ __launch_bounds__(256) void out_gemm(
    const bf16_t* __restrict__ A, const bf16_t* __restrict__ W,
    const float* __restrict__ bias, float* __restrict__ O)
{
  __shared__ bf16_t Als[2 * 128 * 32], Bls[2 * 128 * 32];
  f32x4 acc[4][4];
  f32x4 zero = {0.f, 0.f, 0.f, 0.f};
#pragma unroll
  for (int i = 0; i < 4; ++i)
#pragma unroll
    for (int j = 0; j < 4; ++j) acc[i][j] = zero;

  const int brow = blockIdx.x * 128, bcol = blockIdx.y * 128;
  gemm_tile_128(A, W, Als, Bls, brow, bcol, acc);

  const int tid = threadIdx.x, l = tid & 63, w = tid >> 6;
  const int wr = (w >> 1) * 64, wc = (w & 1) * 64, lh = l >> 4, r15 = l & 15;
#pragma unroll
  for (int ni = 0; ni < 4; ++ni) {
    int col = bcol + wc + ni * 16 + r15;
    float bz = bias[col];
#pragma unroll
    for (int mi = 0; mi < 4; ++mi) {
      int row0 = brow + wr + mi * 16 + lh * 4;
#pragma unroll
      for (int j = 0; j < 4; ++j)
        O[(size_t)(row0 + j) * D_MODEL + col] = acc[mi][ni][j] + bz;
    }
  }
}

// ---------------- causal flash attention ----------------
// Q (pre-scaled), K row-major [B*T][1024]; Vt [B][1024][2048]; O bf16 [B*T][1024]
// Folded-triangle: block does q-tiles {pair, 31-pair} = 33 kv-tiles uniformly.
// Swapped-operand MFMAs: P and O are lane-local in q (lane r15 = q-row).
__device__ __forceinline__ void stage_kv(const bf16_t* Kg, const bf16_t* Vg,
                                         bf16_t* Kd, bf16_t* Vd, int kv0, int w, int l) {
#pragma unroll
  for (int i = 0; i < 2; ++i) {
    int c = w * 2 + i;
    int rr = c * 8 + (l >> 3);
    int gcol = ((l & 7) ^ ((l >> 3) & 7)) * 8;
    gload_lds16(Kg + (size_t)(kv0 + rr) * D_MODEL + gcol, Kd + c * 512);
    gload_lds16(Vg + (size_t)rr * T_SEQ + kv0 + gcol, Vd + c * 512);
  }
}

__global__ __launch_bounds__(256) void flash_attn(
    const bf16_t* __restrict__ Qm, const bf16_t* __restrict__ Km,
    const bf16_t* __restrict__ Vtg, bf16_t* __restrict__ Om)
{
  __shared__ bf16_t Kls[2][64 * 64];
  __shared__ bf16_t Vls[2][64 * 64];
  __shared__ bf16_t Pls[4][16 * 64];

  const int tid = threadIdx.x, l = tid & 63, w = tid >> 6;
  const int lh = l >> 4, r15 = l & 15;

  const int lid = blockIdx.x;
  const int xcd = lid & 7;
  const int idx = lid >> 3;
  const int pair = idx & 15;
  const int bh = xcd + 8 * (idx >> 4);
  const int b = bh >> 4, h = bh & 15;
  const int qtA = pair, qtB = 31 - pair;

  const size_t baseQ = (size_t)b * T_SEQ * D_MODEL + h * 64;
  const size_t baseVt = (size_t)b * (D_MODEL * T_SEQ) + (size_t)(h * 64) * T_SEQ;
  const bf16_t* Kg = Km + baseQ;
  const bf16_t* Vg = Vtg + baseVt;

  int qw = qtA * 64 + w * 16;

  // Q fragments (B-operand layout): q = qw + r15, k = kh*32 + lh*8
  bf16x8 qf[2];
  {
    const bf16_t* qp = Qm + baseQ + (size_t)(qw + r15) * D_MODEL + lh * 8;
    qf[0] = *(const bf16x8*)(qp);
    qf[1] = *(const bf16x8*)(qp + 32);
  }

  float l_r = 0.f;
  f32x4 o_acc[4];
  const f32x4 zero = {0.f, 0.f, 0.f, 0.f};
#pragma unroll
  for (int n = 0; n < 4; ++n) o_acc[n] = zero;

  bf16_t* P = &Pls[w][0];
  const int NT = 33;

  stage_kv(Kg, Vg, Kls[0], Vls[0], 0, w, l);

  for (int t = 0; t < NT; ++t) {
    const int buf = t & 1;
    if (t + 1 < NT) {
      const int nt = t + 1;
      const int nkv0 = (nt <= qtA) ? nt * 64 : (nt - qtA - 1) * 64;
      stage_kv(Kg, Vg, Kls[buf ^ 1], Vls[buf ^ 1], nkv0, w, l);
      WAITVM(4);
    } else {
      WAITVM(0);
    }
    __builtin_amdgcn_s_barrier();

    const int kv0 = (t <= qtA) ? t * 64 : (t - qtA - 1) * 64;
    const bool diag = (t == qtA) || (t == NT - 1);
    const bf16_t* Kb = Kls[buf];
    const bf16_t* Vb = Vls[buf];

    // ---- S^T = K Q^T : sf[n][j] = S[q = qw+r15][kv = kv0 + n*16 + lh*4 + j] ----
    f32x4 sf[4];
    __builtin_amdgcn_s_setprio(1);
#pragma unroll
    for (int n = 0; n < 4; ++n) {
      const int kvc = n * 16 + r15;
      const int sw = kvc & 7;
      bf16x8 kf0 = *(const bf16x8*)(Kb + kvc * 64 + ((lh ^ sw) * 8));
      bf16x8 kf1 = *(const bf16x8*)(Kb + kvc * 64 + (((4 + lh) ^ sw) * 8));
      f32x4 a = zero;
      a = __builtin_amdgcn_mfma_f32_16x16x32_bf16(kf0, qf[0], a, 0, 0, 0);
      a = __builtin_amdgcn_mfma_f32_16x16x32_bf16(kf1, qf[1], a, 0, 0, 0);
      sf[n] = a;
    }
    __builtin_amdgcn_s_setprio(0);

    // ---- p = exp2(s) (Q pre-scaled); mask on diagonal; pack P (lane-local q) ----
    const int qrow = qw + r15;
#pragma unroll
    for (int n = 0; n < 4; ++n) {
      float pv[4];
      if (diag) {
#pragma unroll
        for (int j = 0; j < 4; ++j) {
          const int kvcol = kv0 + n * 16 + lh * 4 + j;
          float p = fast_exp2(sf[n][j]);
          if (kvcol > qrow) p = 0.f;
          pv[j] = p;
          l_r += p;
        }
      } else {
#pragma unroll
        for (int j = 0; j < 4; ++j) {
          float p = fast_exp2(sf[n][j]);
          pv[j] = p;
          l_r += p;
        }
      }
      bf16x4 pk = { (bf16_t)pv[0], (bf16_t)pv[1], (bf16_t)pv[2], (bf16_t)pv[3] };
      const int slot = n * 2 + (lh >> 1);
      *(bf16x4*)(P + r15 * 64 + ((slot ^ (r15 & 7)) * 8) + (lh & 1) * 4) = pk;
    }

    // ---- O += (P V) : swapped -> o_acc[n] has col=q (r15), row=d (n*16+lh*4+j) ----
    bf16x8 pa0, pa1;
    {
      const int sw = r15 & 7;
      pa0 = *(const bf16x8*)(P + r15 * 64 + ((lh ^ sw) * 8));
      pa1 = *(const bf16x8*)(P + r15 * 64 + (((4 + lh) ^ sw) * 8));
    }
    __builtin_amdgcn_s_setprio(1);
#pragma unroll
    for (int n = 0; n < 4; ++n) {
      const int d = n * 16 + r15;
      const int sw = d & 7;
      bf16x8 vf0 = *(const bf16x8*)(Vb + d * 64 + ((lh ^ sw) * 8));
      bf16x8 vf1 = *(const bf16x8*)(Vb + d * 64 + (((4 + lh) ^ sw) * 8));
      o_acc[n] = __builtin_amdgcn_mfma_f32_16x16x32_bf16(vf0, pa0, o_acc[n], 0, 0, 0);
      o_acc[n] = __builtin_amdgcn_mfma_f32_16x16x32_bf16(vf1, pa1, o_acc[n], 0, 0, 0);
    }
    __builtin_amdgcn_s_setprio(0);

    __builtin_amdgcn_s_barrier();

    if (t == qtA) {
      // epilogue for q-tile A (O row = q = qw+r15, cols d = n*16+lh*4+j)
      float ls = l_r;
      ls += __shfl_xor(ls, 16, 64);
      ls += __shfl_xor(ls, 32, 64);
      const float invl = 1.f / ls;
      bf16_t* orow = Om + (size_t)(b * T_SEQ + qw + r15) * D_MODEL + h * 64;
#pragma unroll
      for (int n = 0; n < 4; ++n) {
        bf16x4 pk = { (bf16_t)(o_acc[n][0] * invl), (bf16_t)(o_acc[n][1] * invl),
                      (bf16_t)(o_acc[n][2] * invl), (bf16_t)(o_acc[n][3] * invl) };
        *(bf16x4*)(orow + n * 16 + lh * 4) = pk;
      }
      // switch to q-tile B
      qw = qtB * 64 + w * 16;
      const bf16_t* qp = Qm + baseQ + (size_t)(qw + r15) * D_MODEL + lh * 8;
      qf[0] = *(const bf16x8*)(qp);
      qf[1] = *(const bf16x8*)(qp + 32);
      l_r = 0.f;
#pragma unroll
      for (int n = 0; n < 4; ++n) o_acc[n] = zero;
    }
  }

  // epilogue for q-tile B
  float ls = l_r;
  ls += __shfl_xor(ls, 16, 64);
  ls += __shfl_xor(ls, 32, 64);
  const float invl = 1.f / ls;
  bf16_t* orow = Om + (size_t)(b * T_SEQ + qw + r15) * D_MODEL + h * 64;
#pragma unroll
  for (int n = 0; n < 4; ++n) {
    bf16x4 pk = { (bf16_t)(o_acc[n][0] * invl), (bf16_t)(o_acc[n][1] * invl),
                  (bf16_t)(o_acc[n][2] * invl), (bf16_t)(o_acc[n][3] * invl) };
    *(bf16x4*)(orow + n * 16 + lh * 4) = pk;
  }
}

// ---------------- host launch ----------------
extern "C" void kernel_launch(void* const* d_in, const int* in_sizes, int n_in,
                              void* d_out, int out_size, void* d_ws, size_t ws_size,
                              hipStream_t stream) {
  const float* x  = (const float*)d_in[0];
  const float* wq = (const float*)d_in[1];
  const float* bq = (const float*)d_in[2];
  const float* wk = (const float*)d_in[3];
  const float* bk = (const float*)d_in[4];
  const float* wv = (const float*)d_in[5];
  const float* bv = (const float*)d_in[6];
  const float* wo = (const float*)d_in[7];
  const float* bo = (const float*)d_in[8];

  char* ws = (char*)d_ws;
  const size_t MB = 1024 * 1024;
  bf16_t* xb  = (bf16_t*)(ws);
  bf16_t* wqb = (bf16_t*)(ws + 8 * MB);
  bf16_t* wkb = (bf16_t*)(ws + 10 * MB);
  bf16_t* wvb = (bf16_t*)(ws + 12 * MB);
  bf16_t* wob = (bf16_t*)(ws + 14 * MB);
  bf16_t* qb  = (bf16_t*)(ws + 16 * MB);
  bf16_t* kb  = (bf16_t*)(ws + 24 * MB);
  bf16_t* vtb = (bf16_t*)(ws + 32 * MB);  // V^T [B][1024][2048]
  bf16_t* ob  = (bf16_t*)(ws + 40 * MB);

  CastArgs ca;
  ca.src[0] = x;  ca.dst[0] = xb;
  ca.src[1] = wq; ca.dst[1] = wqb;
  ca.src[2] = wk; ca.dst[2] = wkb;
  ca.src[3] = wv; ca.dst[3] = wvb;
  ca.src[4] = wo; ca.dst[4] = wob;
  cast_all<<<8192, 256, 0, stream>>>(ca);

  QKVArgs qa;
  qa.A = xb;
  qa.W[0] = wqb; qa.W[1] = wkb; qa.W[2] = wvb;
  qa.bias[0] = bq; qa.bias[1] = bk; qa.bias[2] = bv;
  qa.out[0] = qb; qa.out[1] = kb; qa.out[2] = vtb;
  qkv_gemm<<<dim3(32, 8, 3), 256, 0, stream>>>(qa);

  flash_attn<<<512, 256, 0, stream>>>(qb, kb, vtb, ob);

  out_gemm<<<dim3(32, 8), 256, 0, stream>>>(ob, wob, bo, (float*)d_out);
}

// Round 6
// 113.037 us; speedup vs baseline: 1.0676x; 1.0676x over previous
//
#include <hip/hip_runtime.h>
#include <hip/hip_bf16.h>

typedef __bf16 bf16_t;
typedef __bf16 bf16x8 __attribute__((ext_vector_type(8)));
typedef __bf16 bf16x4 __attribute__((ext_vector_type(4)));
typedef float f32x4 __attribute__((ext_vector_type(4)));
typedef unsigned int u32;

#define D_MODEL 1024
#define T_SEQ   2048
#define N_HEADS 16

#define WAITVM(N) asm volatile("s_waitcnt vmcnt(" #N ")" ::: "memory")

__device__ __forceinline__ void gload_lds16(const void* g, void* l) {
  __builtin_amdgcn_global_load_lds((const __attribute__((address_space(1))) u32*)g,
                                   (__attribute__((address_space(3))) u32*)l, 16, 0, 0);
}

__device__ __forceinline__ float fast_exp2(float x) {
#if __has_builtin(__builtin_amdgcn_exp2f)
  return __builtin_amdgcn_exp2f(x);
#else
  return __expf(x * 0.69314718056f);
#endif
}

// ---------------- fused fp32->bf16 cast (x + 4 weights) ----------------
struct CastArgs { const float* src[5]; bf16_t* dst[5]; };

__global__ __launch_bounds__(256) void cast_all(CastArgs p) {
  unsigned i = (blockIdx.x * 256u + threadIdx.x) * 4u;
  int seg; unsigned off;
  if (i < 4194304u) { seg = 0; off = i; }
  else { unsigned r = i - 4194304u; seg = 1 + (int)(r >> 20); off = r & 1048575u; }
  const float4 v = *(const float4*)(p.src[seg] + off);
  bf16x4 o = { (bf16_t)v.x, (bf16_t)v.y, (bf16_t)v.z, (bf16_t)v.w };
  *(bf16x4*)(p.dst[seg] + off) = o;
}

// ---------------- 64x128 bf16 GEMM tile, C = A @ W^T ----------------
// LDS step buffer = 12 chunks of 16 rows x 32 k (A: chunks 0-3, B: chunks 4-11)
// Triple-buffered, 2-deep prefetch, counted vmcnt.
__device__ __forceinline__ void stage_ab64(
    const bf16_t* __restrict__ A, const bf16_t* __restrict__ W,
    bf16_t* buf, int brow, int bcol, int k0, int w, int l) {
  const int srow = l >> 2;
  const int scol = ((l & 3) ^ ((l >> 3) & 3)) * 8;
#pragma unroll
  for (int i = 0; i < 3; ++i) {
    int ch = w * 3 + i;
    const bf16_t* src = (ch < 4)
      ? A + (size_t)(brow + ch * 16 + srow) * D_MODEL + k0 + scol
      : W + (size_t)(bcol + (ch - 4) * 16 + srow) * D_MODEL + k0 + scol;
    gload_lds16(src, buf + ch * 512);
  }
}

// acc[2][4]: wave owns 32x64 (wr=(w>>1)*32, wc=(w&1)*64)
__device__ __forceinline__ void gemm_tile_64(
    const bf16_t* __restrict__ A, const bf16_t* __restrict__ W,
    bf16_t* bufs, int brow, int bcol, f32x4 acc[2][4])
{
  const int tid = threadIdx.x;
  const int l = tid & 63, w = tid >> 6;
  const int wr = (w >> 1) * 32, wc = (w & 1) * 64;
  const int lh = l >> 4, r15 = l & 15;
  const int NS = D_MODEL / 32;   // 32 k-steps

  stage_ab64(A, W, bufs + 0 * 6144, brow, bcol, 0, w, l);
  stage_ab64(A, W, bufs + 1 * 6144, brow, bcol, 32, w, l);

  for (int t = 0; t < NS; ++t) {
    bf16_t* bb = bufs + (t % 3) * 6144;
    if (t + 2 < NS) {
      stage_ab64(A, W, bufs + ((t + 2) % 3) * 6144, brow, bcol, (t + 2) * 32, w, l);
      WAITVM(6);
    } else if (t + 1 < NS) {
      WAITVM(3);
    } else {
      WAITVM(0);
    }
    __builtin_amdgcn_s_barrier();

    bf16x8 af[2], bfr[4];
#pragma unroll
    for (int mi = 0; mi < 2; ++mi) {
      int rr = wr + mi * 16 + r15;
      int s = lh ^ ((rr >> 1) & 3);
      af[mi] = *(const bf16x8*)(bb + rr * 32 + s * 8);
    }
#pragma unroll
    for (int ni = 0; ni < 4; ++ni) {
      int rr = wc + ni * 16 + r15;
      int s = lh ^ ((rr >> 1) & 3);
      bfr[ni] = *(const bf16x8*)(bb + 2048 + rr * 32 + s * 8);
    }
    __builtin_amdgcn_s_setprio(1);
#pragma unroll
    for (int mi = 0; mi < 2; ++mi)
#pragma unroll
      for (int ni = 0; ni < 4; ++ni)
        acc[mi][ni] = __builtin_amdgcn_mfma_f32_16x16x32_bf16(af[mi], bfr[ni], acc[mi][ni], 0, 0, 0);
    __builtin_amdgcn_s_setprio(0);
    __builtin_amdgcn_s_barrier();
  }
}

// ---------------- QKV projection: grid (64, 8, 3) ----------------
// z==0 (Q): output pre-scaled by 0.125*log2(e). z==2 (V): transposed store.
struct QKVArgs {
  const bf16_t* A;
  const bf16_t* W[3];
  const float* bias[3];
  bf16_t* out[3];
};

#define QSCL 0.18033688011112042f   // 0.125 * log2(e)

__global__ __launch_bounds__(256) void qkv_gemm(QKVArgs p) {
  __shared__ bf16_t bufs[3 * 6144];
  f32x4 acc[2][4];
  f32x4 zero = {0.f, 0.f, 0.f, 0.f};
#pragma unroll
  for (int i = 0; i < 2; ++i)
#pragma unroll
    for (int j = 0; j < 4; ++j) acc[i][j] = zero;

  const int z = blockIdx.z;
  const int brow = blockIdx.x * 64, bcol = blockIdx.y * 128;
  gemm_tile_64(p.A, p.W[z], bufs, brow, bcol, acc);

  const int tid = threadIdx.x, l = tid & 63, w = tid >> 6;
  const int wr = (w >> 1) * 32, wc = (w & 1) * 64, lh = l >> 4, r15 = l & 15;
  const float* bias = p.bias[z];
  bf16_t* O = p.out[z];

  if (z == 2) {
#pragma unroll
    for (int ni = 0; ni < 4; ++ni) {
      int col = bcol + wc + ni * 16 + r15;
      float bz = bias[col];
#pragma unroll
      for (int mi = 0; mi < 2; ++mi) {
        int row0 = brow + wr + mi * 16 + lh * 4;
        int bb = row0 >> 11, t0 = row0 & 2047;
        bf16x4 pk;
#pragma unroll
        for (int j = 0; j < 4; ++j) pk[j] = (bf16_t)(acc[mi][ni][j] + bz);
        *(bf16x4*)(O + (size_t)bb * (D_MODEL * T_SEQ) + (size_t)col * T_SEQ + t0) = pk;
      }
    }
  } else if (z == 0) {
#pragma unroll
    for (int ni = 0; ni < 4; ++ni) {
      int col = bcol + wc + ni * 16 + r15;
      float bz = bias[col];
#pragma unroll
      for (int mi = 0; mi < 2; ++mi) {
        int row0 = brow + wr + mi * 16 + lh * 4;
#pragma unroll
        for (int j = 0; j < 4; ++j)
          O[(size_t)(row0 + j) * D_MODEL + col] = (bf16_t)((acc[mi][ni][j] + bz) * QSCL);
      }
    }
  } else {
#pragma unroll
    for (int ni = 0; ni < 4; ++ni) {
      int col = bcol + wc + ni * 16 + r15;
      float bz = bias[col];
#pragma unroll
      for (int mi = 0; mi < 2; ++mi) {
        int row0 = brow + wr + mi * 16 + lh * 4;
#pragma unroll
        for (int j = 0; j < 4; ++j)
          O[(size_t)(row0 + j) * D_MODEL + col] = (bf16_t)(acc[mi][ni][j] + bz);
      }
    }
  }
}

// ---------------- output projection: grid (64, 8), fp32 epilogue ----------
__global__ __launch_bounds__(256) void out_gemm(
    const bf16_t* __restrict__ A, const bf16_t* __restrict__ W,
    const float* __restrict__ bias, float* __restrict__ O)
{
  __shared__ bf16_t bufs[3 * 6144];
  f32x4 acc[2][4];
  f32x4 zero = {0.f, 0.f, 0.f, 0.f};
#pragma unroll
  for (int i = 0; i < 2; ++i)
#pragma unroll
    for (int j = 0; j < 4; ++j) acc[i][j] = zero;

  const int brow = blockIdx.x * 64, bcol = blockIdx.y * 128;
  gemm_tile_64(A, W, bufs, brow, bcol, acc);

  const int tid = threadIdx.x, l = tid & 63, w = tid >> 6;
  const int wr = (w >> 1) * 32, wc = (w & 1) * 64, lh = l >> 4, r15 = l & 15;
#pragma unroll
  for (int ni = 0; ni < 4; ++ni) {
    int col = bcol + wc + ni * 16 + r15;
    float bz = bias[col];
#pragma unroll
    for (int mi = 0; mi < 2; ++mi) {
      int row0 = brow + wr + mi * 16 + lh * 4;
#pragma unroll
      for (int j = 0; j < 4; ++j)
        O[(size_t)(row0 + j) * D_MODEL + col] = acc[mi][ni][j] + bz;
    }
  }
}

// ---------------- causal flash attention ----------------
// Q (pre-scaled), K row-major [B*T][1024]; Vt [B][1024][2048]; O bf16 [B*T][1024]
// Folded-triangle: block does q-tiles {pair, 31-pair} = 33 kv-tiles uniformly.
// Swapped-operand MFMAs: P and O are lane-local in q (lane r15 = q-row).
__device__ __forceinline__ void stage_kv(const bf16_t* Kg, const bf16_t* Vg,
                                         bf16_t* Kd, bf16_t* Vd, int kv0, int w, int l) {
#pragma unroll
  for (int i = 0; i < 2; ++i) {
    int c = w * 2 + i;
    int rr = c * 8 + (l >> 3);
    int gcol = ((l & 7) ^ ((l >> 3) & 7)) * 8;
    gload_lds16(Kg + (size_t)(kv0 + rr) * D_MODEL + gcol, Kd + c * 512);
    gload_lds16(Vg + (size_t)rr * T_SEQ + kv0 + gcol, Vd + c * 512);
  }
}

__global__ __launch_bounds__(256) void flash_attn(
    const bf16_t* __restrict__ Qm, const bf16_t* __restrict__ Km,
    const bf16_t* __restrict__ Vtg, bf16_t* __restrict__ Om)
{
  __shared__ bf16_t Kls[2][64 * 64];
  __shared__ bf16_t Vls[2][64 * 64];
  __shared__ bf16_t Pls[4][16 * 64];

  const int tid = threadIdx.x, l = tid & 63, w = tid >> 6;
  const int lh = l >> 4, r15 = l & 15;

  const int lid = blockIdx.x;
  const int xcd = lid & 7;
  const int idx = lid >> 3;
  const int pair = idx & 15;
  const int bh = xcd + 8 * (idx >> 4);
  const int b = bh >> 4, h = bh & 15;
  const int qtA = pair, qtB = 31 - pair;

  const size_t baseQ = (size_t)b * T_SEQ * D_MODEL + h * 64;
  const size_t baseVt = (size_t)b * (D_MODEL * T_SEQ) + (size_t)(h * 64) * T_SEQ;
  const bf16_t* Kg = Km + baseQ;
  const bf16_t* Vg = Vtg + baseVt;

  int qw = qtA * 64 + w * 16;

  // Q fragments (B-operand layout): q = qw + r15, k = kh*32 + lh*8
  bf16x8 qf[2];
  {
    const bf16_t* qp = Qm + baseQ + (size_t)(qw + r15) * D_MODEL + lh * 8;
    qf[0] = *(const bf16x8*)(qp);
    qf[1] = *(const bf16x8*)(qp + 32);
  }

  float l_r = 0.f;
  f32x4 o_acc[4];
  const f32x4 zero = {0.f, 0.f, 0.f, 0.f};
#pragma unroll
  for (int n = 0; n < 4; ++n) o_acc[n] = zero;

  bf16_t* P = &Pls[w][0];
  const int NT = 33;

  stage_kv(Kg, Vg, Kls[0], Vls[0], 0, w, l);

  for (int t = 0; t < NT; ++t) {
    const int buf = t & 1;
    if (t + 1 < NT) {
      const int nt = t + 1;
      const int nkv0 = (nt <= qtA) ? nt * 64 : (nt - qtA - 1) * 64;
      stage_kv(Kg, Vg, Kls[buf ^ 1], Vls[buf ^ 1], nkv0, w, l);
      WAITVM(4);
    } else {
      WAITVM(0);
    }
    __builtin_amdgcn_s_barrier();

    const int kv0 = (t <= qtA) ? t * 64 : (t - qtA - 1) * 64;
    const bool diag = (t == qtA) || (t == NT - 1);
    const bf16_t* Kb = Kls[buf];
    const bf16_t* Vb = Vls[buf];

    // ---- S^T = K Q^T : sf[n][j] = S[q = qw+r15][kv = kv0 + n*16 + lh*4 + j] ----
    f32x4 sf[4];
    __builtin_amdgcn_s_setprio(1);
#pragma unroll
    for (int n = 0; n < 4; ++n) {
      const int kvc = n * 16 + r15;
      const int sw = kvc & 7;
      bf16x8 kf0 = *(const bf16x8*)(Kb + kvc * 64 + ((lh ^ sw) * 8));
      bf16x8 kf1 = *(const bf16x8*)(Kb + kvc * 64 + (((4 + lh) ^ sw) * 8));
      f32x4 a = zero;
      a = __builtin_amdgcn_mfma_f32_16x16x32_bf16(kf0, qf[0], a, 0, 0, 0);
      a = __builtin_amdgcn_mfma_f32_16x16x32_bf16(kf1, qf[1], a, 0, 0, 0);
      sf[n] = a;
    }
    __builtin_amdgcn_s_setprio(0);

    // ---- p = exp2(s) (Q pre-scaled); mask on diagonal; pack P (lane-local q) ----
    const int qrow = qw + r15;
#pragma unroll
    for (int n = 0; n < 4; ++n) {
      float pv[4];
      if (diag) {
#pragma unroll
        for (int j = 0; j < 4; ++j) {
          const int kvcol = kv0 + n * 16 + lh * 4 + j;
          float p = fast_exp2(sf[n][j]);
          if (kvcol > qrow) p = 0.f;
          pv[j] = p;
          l_r += p;
        }
      } else {
#pragma unroll
        for (int j = 0; j < 4; ++j) {
          float p = fast_exp2(sf[n][j]);
          pv[j] = p;
          l_r += p;
        }
      }
      bf16x4 pk = { (bf16_t)pv[0], (bf16_t)pv[1], (bf16_t)pv[2], (bf16_t)pv[3] };
      const int slot = n * 2 + (lh >> 1);
      *(bf16x4*)(P + r15 * 64 + ((slot ^ (r15 & 7)) * 8) + (lh & 1) * 4) = pk;
    }

    // ---- O += (P V) : swapped -> o_acc[n] has col=q (r15), row=d (n*16+lh*4+j) ----
    bf16x8 pa0, pa1;
    {
      const int sw = r15 & 7;
      pa0 = *(const bf16x8*)(P + r15 * 64 + ((lh ^ sw) * 8));
      pa1 = *(const bf16x8*)(P + r15 * 64 + (((4 + lh) ^ sw) * 8));
    }
    __builtin_amdgcn_s_setprio(1);
#pragma unroll
    for (int n = 0; n < 4; ++n) {
      const int d = n * 16 + r15;
      const int sw = d & 7;
      bf16x8 vf0 = *(const bf16x8*)(Vb + d * 64 + ((lh ^ sw) * 8));
      bf16x8 vf1 = *(const bf16x8*)(Vb + d * 64 + (((4 + lh) ^ sw) * 8));
      o_acc[n] = __builtin_amdgcn_mfma_f32_16x16x32_bf16(vf0, pa0, o_acc[n], 0, 0, 0);
      o_acc[n] = __builtin_amdgcn_mfma_f32_16x16x32_bf16(vf1, pa1, o_acc[n], 0, 0, 0);
    }
    __builtin_amdgcn_s_setprio(0);

    __builtin_amdgcn_s_barrier();

    if (t == qtA) {
      float ls = l_r;
      ls += __shfl_xor(ls, 16, 64);
      ls += __shfl_xor(ls, 32, 64);
      const float invl = 1.f / ls;
      bf16_t* orow = Om + (size_t)(b * T_SEQ + qw + r15) * D_MODEL + h * 64;
#pragma unroll
      for (int n = 0; n < 4; ++n) {
        bf16x4 pk = { (bf16_t)(o_acc[n][0] * invl), (bf16_t)(o_acc[n][1] * invl),
                      (bf16_t)(o_acc[n][2] * invl), (bf16_t)(o_acc[n][3] * invl) };
        *(bf16x4*)(orow + n * 16 + lh * 4) = pk;
      }
      qw = qtB * 64 + w * 16;
      const bf16_t* qp = Qm + baseQ + (size_t)(qw + r15) * D_MODEL + lh * 8;
      qf[0] = *(const bf16x8*)(qp);
      qf[1] = *(const bf16x8*)(qp + 32);
      l_r = 0.f;
#pragma unroll
      for (int n = 0; n < 4; ++n) o_acc[n] = zero;
    }
  }

  // epilogue for q-tile B
  float ls = l_r;
  ls += __shfl_xor(ls, 16, 64);
  ls += __shfl_xor(ls, 32, 64);
  const float invl = 1.f / ls;
  bf16_t* orow = Om + (size_t)(b * T_SEQ + qw + r15) * D_MODEL + h * 64;
#pragma unroll
  for (int n = 0; n < 4; ++n) {
    bf16x4 pk = { (bf16_t)(o_acc[n][0] * invl), (bf16_t)(o_acc[n][1] * invl),
                  (bf16_t)(o_acc[n][2] * invl), (bf16_t)(o_acc[n][3] * invl) };
    *(bf16x4*)(orow + n * 16 + lh * 4) = pk;
  }
}

// ---------------- host launch ----------------
extern "C" void kernel_launch(void* const* d_in, const int* in_sizes, int n_in,
                              void* d_out, int out_size, void* d_ws, size_t ws_size,
                              hipStream_t stream) {
  const float* x  = (const float*)d_in[0];
  const float* wq = (const float*)d_in[1];
  const float* bq = (const float*)d_in[2];
  const float* wk = (const float*)d_in[3];
  const float* bk = (const float*)d_in[4];
  const float* wv = (const float*)d_in[5];
  const float* bv = (const float*)d_in[6];
  const float* wo = (const float*)d_in[7];
  const float* bo = (const float*)d_in[8];

  char* ws = (char*)d_ws;
  const size_t MB = 1024 * 1024;
  bf16_t* xb  = (bf16_t*)(ws);
  bf16_t* wqb = (bf16_t*)(ws + 8 * MB);
  bf16_t* wkb = (bf16_t*)(ws + 10 * MB);
  bf16_t* wvb = (bf16_t*)(ws + 12 * MB);
  bf16_t* wob = (bf16_t*)(ws + 14 * MB);
  bf16_t* qb  = (bf16_t*)(ws + 16 * MB);
  bf16_t* kb  = (bf16_t*)(ws + 24 * MB);
  bf16_t* vtb = (bf16_t*)(ws + 32 * MB);  // V^T [B][1024][2048]
  bf16_t* ob  = (bf16_t*)(ws + 40 * MB);

  CastArgs ca;
  ca.src[0] = x;  ca.dst[0] = xb;
  ca.src[1] = wq; ca.dst[1] = wqb;
  ca.src[2] = wk; ca.dst[2] = wkb;
  ca.src[3] = wv; ca.dst[3] = wvb;
  ca.src[4] = wo; ca.dst[4] = wob;
  cast_all<<<8192, 256, 0, stream>>>(ca);

  QKVArgs qa;
  qa.A = xb;
  qa.W[0] = wqb; qa.W[1] = wkb; qa.W[2] = wvb;
  qa.bias[0] = bq; qa.bias[1] = bk; qa.bias[2] = bv;
  qa.out[0] = qb; qa.out[1] = kb; qa.out[2] = vtb;
  qkv_gemm<<<dim3(64, 8, 3), 256, 0, stream>>>(qa);

  flash_attn<<<512, 256, 0, stream>>>(qb, kb, vtb, ob);

  out_gemm<<<dim3(64, 8), 256, 0, stream>>>(ob, wob, bo, (float*)d_out);
}

// Round 7
// 101.324 us; speedup vs baseline: 1.1910x; 1.1156x over previous
//
#include <hip/hip_runtime.h>
#include <hip/hip_bf16.h>

typedef __bf16 bf16_t;
typedef __bf16 bf16x8 __attribute__((ext_vector_type(8)));
typedef __bf16 bf16x4 __attribute__((ext_vector_type(4)));
typedef float f32x4 __attribute__((ext_vector_type(4)));
typedef unsigned int u32;

#define D_MODEL 1024
#define T_SEQ   2048
#define N_HEADS 16

#define WAITVM(N) asm volatile("s_waitcnt vmcnt(" #N ")" ::: "memory")

__device__ __forceinline__ void gload_lds16(const void* g, void* l) {
  __builtin_amdgcn_global_load_lds((const __attribute__((address_space(1))) u32*)g,
                                   (__attribute__((address_space(3))) u32*)l, 16, 0, 0);
}

__device__ __forceinline__ float fast_exp2(float x) {
#if __has_builtin(__builtin_amdgcn_exp2f)
  return __builtin_amdgcn_exp2f(x);
#else
  return __expf(x * 0.69314718056f);
#endif
}

// ---------------- fused fp32->bf16 cast (x + 4 weights) ----------------
struct CastArgs { const float* src[5]; bf16_t* dst[5]; };

__global__ __launch_bounds__(256) void cast_all(CastArgs p) {
  unsigned i = (blockIdx.x * 256u + threadIdx.x) * 4u;
  int seg; unsigned off;
  if (i < 4194304u) { seg = 0; off = i; }
  else { unsigned r = i - 4194304u; seg = 1 + (int)(r >> 20); off = r & 1048575u; }
  const float4 v = *(const float4*)(p.src[seg] + off);
  bf16x4 o = { (bf16_t)v.x, (bf16_t)v.y, (bf16_t)v.z, (bf16_t)v.w };
  *(bf16x4*)(p.dst[seg] + off) = o;
}

#define QSCL 0.18033688011112042f   // 0.125 * log2(e)

// ============== fused QKV: 256x192 tile, BK=64, 4-phase, 512 thr ==============
// A [4096][1024] bf16; W q/k/v [1024][1024] bf16; out: Q(scaled),K row-major,
// V transposed vt[b][dcol][t]. Grid: 256 blocks (bx=row-tile 0..15, by=col-tile
// 0..15 over N=3072). LDS: 2 x (A 256x64 + B 192x64) = 112 KB, chunk-swizzled.
struct QKVArgs {
  const bf16_t* A;
  const bf16_t* W[3];
  const float* bias[3];
  bf16_t* out[3];
};

__global__ __launch_bounds__(512, 2) void qkv_gemm(QKVArgs p) {
  __shared__ bf16_t lds[2 * 28672];   // [buf][A:16384 | B:12288]

  const int tid = threadIdx.x;
  const int l = tid & 63, wid = tid >> 6;
  const int lh = l >> 4, r15 = l & 15;

  const int lid = blockIdx.x;
  const int bx = lid >> 4, by = lid & 15;     // consecutive lids share bx (A-strip)
  const int brow = bx * 256;
  const int gcol0 = by * 192;

  const int wr = (wid >> 2) * 128;            // 2 M-warps
  const int wc = (wid & 3) * 48;              // 4 N-warps x 48 cols
  const int wrc = (wr >> 4);                  // A chunk base
  const int wcc = (wc >> 4);                  // B chunk base
  const int sA = (lh ^ ((r15 >> 1) & 3)) * 8; // read slot offset (elems)
  const int roff = r15 * 32;

  // staging lane constants
  const int srow = l >> 2;
  const int gs = ((l & 3) ^ ((l >> 3) & 3)) * 8;

  f32x4 acc[8][3];
  const f32x4 zero = {0.f, 0.f, 0.f, 0.f};
#pragma unroll
  for (int i = 0; i < 8; ++i)
#pragma unroll
    for (int j = 0; j < 3; ++j) acc[i][j] = zero;

  const bf16_t* A = p.A;

  // ---- staging helpers (inlined as lambdas) ----
  auto stageA = [&](bf16_t* buf, int k0, int kh) {
#pragma unroll
    for (int i = 0; i < 2; ++i) {
      int c = wid * 2 + i;
      gload_lds16(A + (size_t)(brow + c * 16 + srow) * D_MODEL + k0 + kh * 32 + gs,
                  buf + kh * 8192 + c * 512);
    }
  };
  auto stageB = [&](bf16_t* buf, int k0) {
#pragma unroll
    for (int i = 0; i < 3; ++i) {
      int g = wid * 3 + i;          // 0..23
      int kh = g >= 12;
      int c = g - kh * 12;
      int gcol = gcol0 + c * 16 + srow;
      int z = gcol >> 10;
      const bf16_t* w = (z == 0) ? p.W[0] : ((z == 1) ? p.W[1] : p.W[2]);
      gload_lds16(w + (size_t)(gcol & 1023) * D_MODEL + k0 + kh * 32 + gs,
                  buf + 16384 + kh * 6144 + c * 512);
    }
  };

  // prologue: stage tile 0 fully
  stageA(lds, 0, 0);
  stageA(lds, 0, 1);
  stageB(lds, 0);
  WAITVM(0);
  __builtin_amdgcn_s_barrier();

  for (int t = 0; t < 16; ++t) {
    bf16_t* cur = lds + (t & 1) * 28672;
    bf16_t* nxt = lds + ((t + 1) & 1) * 28672;
    const int k1 = (t + 1) * 64;
    const bool more = (t < 15);

    bf16x8 bfr[3][2];
#pragma unroll
    for (int ph = 0; ph < 4; ++ph) {
      // ds-reads for this phase's mi-pair
      bf16x8 a[2][2];
#pragma unroll
      for (int jj = 0; jj < 2; ++jj)
#pragma unroll
        for (int kh = 0; kh < 2; ++kh)
          a[jj][kh] = *(const bf16x8*)(cur + kh * 8192 + (wrc + 2 * ph + jj) * 512 + roff + sA);
      if (ph == 0) {
#pragma unroll
        for (int ni = 0; ni < 3; ++ni)
#pragma unroll
          for (int kh = 0; kh < 2; ++kh)
            bfr[ni][kh] = *(const bf16x8*)(cur + 16384 + kh * 6144 + (wcc + ni) * 512 + roff + sA);
      }
      // stage one unit of next tile
      if (more) {
        if (ph == 0) stageA(nxt, k1, 0);
        else if (ph == 1) stageA(nxt, k1, 1);
        else if (ph == 2) stageB(nxt, k1);
      }
      __builtin_amdgcn_s_barrier();
      __builtin_amdgcn_s_setprio(1);
#pragma unroll
      for (int jj = 0; jj < 2; ++jj)
#pragma unroll
        for (int ni = 0; ni < 3; ++ni) {
          acc[2 * ph + jj][ni] = __builtin_amdgcn_mfma_f32_16x16x32_bf16(a[jj][0], bfr[ni][0], acc[2 * ph + jj][ni], 0, 0, 0);
          acc[2 * ph + jj][ni] = __builtin_amdgcn_mfma_f32_16x16x32_bf16(a[jj][1], bfr[ni][1], acc[2 * ph + jj][ni], 0, 0, 0);
        }
      __builtin_amdgcn_s_setprio(0);
      if (ph == 3 && more) WAITVM(0);
      __builtin_amdgcn_s_barrier();
    }
  }

  // ---- epilogue ----
#pragma unroll
  for (int ni = 0; ni < 3; ++ni) {
    const int col = gcol0 + wc + ni * 16 + r15;
    const int z = col >> 10;
    const int zc = col & 1023;
    const float* bias = (z == 0) ? p.bias[0] : ((z == 1) ? p.bias[1] : p.bias[2]);
    bf16_t* O = (z == 0) ? p.out[0] : ((z == 1) ? p.out[1] : p.out[2]);
    const float bz = bias[zc];
    if (z == 2) {
#pragma unroll
      for (int mi = 0; mi < 8; ++mi) {
        int row0 = brow + wr + mi * 16 + lh * 4;
        int bb = row0 >> 11, t0 = row0 & 2047;
        bf16x4 pk;
#pragma unroll
        for (int j = 0; j < 4; ++j) pk[j] = (bf16_t)(acc[mi][ni][j] + bz);
        *(bf16x4*)(O + (size_t)bb * (D_MODEL * T_SEQ) + (size_t)zc * T_SEQ + t0) = pk;
      }
    } else if (z == 0) {
#pragma unroll
      for (int mi = 0; mi < 8; ++mi) {
        int row0 = brow + wr + mi * 16 + lh * 4;
#pragma unroll
        for (int j = 0; j < 4; ++j)
          O[(size_t)(row0 + j) * D_MODEL + zc] = (bf16_t)((acc[mi][ni][j] + bz) * QSCL);
      }
    } else {
#pragma unroll
      for (int mi = 0; mi < 8; ++mi) {
        int row0 = brow + wr + mi * 16 + lh * 4;
#pragma unroll
        for (int j = 0; j < 4; ++j)
          O[(size_t)(row0 + j) * D_MODEL + zc] = (bf16_t)(acc[mi][ni][j] + bz);
      }
    }
  }
}

// ---------------- 64x128 GEMM (out projection) ----------------
__device__ __forceinline__ void stage_ab64(
    const bf16_t* __restrict__ A, const bf16_t* __restrict__ W,
    bf16_t* buf, int brow, int bcol, int k0, int w, int l) {
  const int srow = l >> 2;
  const int scol = ((l & 3) ^ ((l >> 3) & 3)) * 8;
#pragma unroll
  for (int i = 0; i < 3; ++i) {
    int ch = w * 3 + i;
    const bf16_t* src = (ch < 4)
      ? A + (size_t)(brow + ch * 16 + srow) * D_MODEL + k0 + scol
      : W + (size_t)(bcol + (ch - 4) * 16 + srow) * D_MODEL + k0 + scol;
    gload_lds16(src, buf + ch * 512);
  }
}

__device__ __forceinline__ void gemm_tile_64(
    const bf16_t* __restrict__ A, const bf16_t* __restrict__ W,
    bf16_t* bufs, int brow, int bcol, f32x4 acc[2][4])
{
  const int tid = threadIdx.x;
  const int l = tid & 63, w = tid >> 6;
  const int wr = (w >> 1) * 32, wc = (w & 1) * 64;
  const int lh = l >> 4, r15 = l & 15;
  const int NS = D_MODEL / 32;

  stage_ab64(A, W, bufs + 0 * 6144, brow, bcol, 0, w, l);
  stage_ab64(A, W, bufs + 1 * 6144, brow, bcol, 32, w, l);

  for (int t = 0; t < NS; ++t) {
    bf16_t* bb = bufs + (t % 3) * 6144;
    if (t + 2 < NS) {
      stage_ab64(A, W, bufs + ((t + 2) % 3) * 6144, brow, bcol, (t + 2) * 32, w, l);
      WAITVM(6);
    } else if (t + 1 < NS) {
      WAITVM(3);
    } else {
      WAITVM(0);
    }
    __builtin_amdgcn_s_barrier();

    bf16x8 af[2], bfr[4];
#pragma unroll
    for (int mi = 0; mi < 2; ++mi) {
      int rr = wr + mi * 16 + r15;
      int s = lh ^ ((rr >> 1) & 3);
      af[mi] = *(const bf16x8*)(bb + rr * 32 + s * 8);
    }
#pragma unroll
    for (int ni = 0; ni < 4; ++ni) {
      int rr = wc + ni * 16 + r15;
      int s = lh ^ ((rr >> 1) & 3);
      bfr[ni] = *(const bf16x8*)(bb + 2048 + rr * 32 + s * 8);
    }
    __builtin_amdgcn_s_setprio(1);
#pragma unroll
    for (int mi = 0; mi < 2; ++mi)
#pragma unroll
      for (int ni = 0; ni < 4; ++ni)
        acc[mi][ni] = __builtin_amdgcn_mfma_f32_16x16x32_bf16(af[mi], bfr[ni], acc[mi][ni], 0, 0, 0);
    __builtin_amdgcn_s_setprio(0);
    __builtin_amdgcn_s_barrier();
  }
}

__global__ __launch_bounds__(256) void out_gemm(
    const bf16_t* __restrict__ A, const bf16_t* __restrict__ W,
    const float* __restrict__ bias, float* __restrict__ O)
{
  __shared__ bf16_t bufs[3 * 6144];
  f32x4 acc[2][4];
  f32x4 zero = {0.f, 0.f, 0.f, 0.f};
#pragma unroll
  for (int i = 0; i < 2; ++i)
#pragma unroll
    for (int j = 0; j < 4; ++j) acc[i][j] = zero;

  const int brow = blockIdx.x * 64, bcol = blockIdx.y * 128;
  gemm_tile_64(A, W, bufs, brow, bcol, acc);

  const int tid = threadIdx.x, l = tid & 63, w = tid >> 6;
  const int wr = (w >> 1) * 32, wc = (w & 1) * 64, lh = l >> 4, r15 = l & 15;
#pragma unroll
  for (int ni = 0; ni < 4; ++ni) {
    int col = bcol + wc + ni * 16 + r15;
    float bz = bias[col];
#pragma unroll
    for (int mi = 0; mi < 2; ++mi) {
      int row0 = brow + wr + mi * 16 + lh * 4;
#pragma unroll
      for (int j = 0; j < 4; ++j)
        O[(size_t)(row0 + j) * D_MODEL + col] = acc[mi][ni][j] + bz;
    }
  }
}

// ---------------- causal flash attention (unchanged from R6) ----------------
__device__ __forceinline__ void stage_kv(const bf16_t* Kg, const bf16_t* Vg,
                                         bf16_t* Kd, bf16_t* Vd, int kv0, int w, int l) {
#pragma unroll
  for (int i = 0; i < 2; ++i) {
    int c = w * 2 + i;
    int rr = c * 8 + (l >> 3);
    int gcol = ((l & 7) ^ ((l >> 3) & 7)) * 8;
    gload_lds16(Kg + (size_t)(kv0 + rr) * D_MODEL + gcol, Kd + c * 512);
    gload_lds16(Vg + (size_t)rr * T_SEQ + kv0 + gcol, Vd + c * 512);
  }
}

__global__ __launch_bounds__(256) void flash_attn(
    const bf16_t* __restrict__ Qm, const bf16_t* __restrict__ Km,
    const bf16_t* __restrict__ Vtg, bf16_t* __restrict__ Om)
{
  __shared__ bf16_t Kls[2][64 * 64];
  __shared__ bf16_t Vls[2][64 * 64];
  __shared__ bf16_t Pls[4][16 * 64];

  const int tid = threadIdx.x, l = tid & 63, w = tid >> 6;
  const int lh = l >> 4, r15 = l & 15;

  const int lid = blockIdx.x;
  const int xcd = lid & 7;
  const int idx = lid >> 3;
  const int pair = idx & 15;
  const int bh = xcd + 8 * (idx >> 4);
  const int b = bh >> 4, h = bh & 15;
  const int qtA = pair, qtB = 31 - pair;

  const size_t baseQ = (size_t)b * T_SEQ * D_MODEL + h * 64;
  const size_t baseVt = (size_t)b * (D_MODEL * T_SEQ) + (size_t)(h * 64) * T_SEQ;
  const bf16_t* Kg = Km + baseQ;
  const bf16_t* Vg = Vtg + baseVt;

  int qw = qtA * 64 + w * 16;

  bf16x8 qf[2];
  {
    const bf16_t* qp = Qm + baseQ + (size_t)(qw + r15) * D_MODEL + lh * 8;
    qf[0] = *(const bf16x8*)(qp);
    qf[1] = *(const bf16x8*)(qp + 32);
  }

  float l_r = 0.f;
  f32x4 o_acc[4];
  const f32x4 zero = {0.f, 0.f, 0.f, 0.f};
#pragma unroll
  for (int n = 0; n < 4; ++n) o_acc[n] = zero;

  bf16_t* P = &Pls[w][0];
  const int NT = 33;

  stage_kv(Kg, Vg, Kls[0], Vls[0], 0, w, l);

  for (int t = 0; t < NT; ++t) {
    const int buf = t & 1;
    if (t + 1 < NT) {
      const int nt = t + 1;
      const int nkv0 = (nt <= qtA) ? nt * 64 : (nt - qtA - 1) * 64;
      stage_kv(Kg, Vg, Kls[buf ^ 1], Vls[buf ^ 1], nkv0, w, l);
      WAITVM(4);
    } else {
      WAITVM(0);
    }
    __builtin_amdgcn_s_barrier();

    const int kv0 = (t <= qtA) ? t * 64 : (t - qtA - 1) * 64;
    const bool diag = (t == qtA) || (t == NT - 1);
    const bf16_t* Kb = Kls[buf];
    const bf16_t* Vb = Vls[buf];

    f32x4 sf[4];
    __builtin_amdgcn_s_setprio(1);
#pragma unroll
    for (int n = 0; n < 4; ++n) {
      const int kvc = n * 16 + r15;
      const int sw = kvc & 7;
      bf16x8 kf0 = *(const bf16x8*)(Kb + kvc * 64 + ((lh ^ sw) * 8));
      bf16x8 kf1 = *(const bf16x8*)(Kb + kvc * 64 + (((4 + lh) ^ sw) * 8));
      f32x4 a = zero;
      a = __builtin_amdgcn_mfma_f32_16x16x32_bf16(kf0, qf[0], a, 0, 0, 0);
      a = __builtin_amdgcn_mfma_f32_16x16x32_bf16(kf1, qf[1], a, 0, 0, 0);
      sf[n] = a;
    }
    __builtin_amdgcn_s_setprio(0);

    const int qrow = qw + r15;
#pragma unroll
    for (int n = 0; n < 4; ++n) {
      float pv[4];
      if (diag) {
#pragma unroll
        for (int j = 0; j < 4; ++j) {
          const int kvcol = kv0 + n * 16 + lh * 4 + j;
          float pp = fast_exp2(sf[n][j]);
          if (kvcol > qrow) pp = 0.f;
          pv[j] = pp;
          l_r += pp;
        }
      } else {
#pragma unroll
        for (int j = 0; j < 4; ++j) {
          float pp = fast_exp2(sf[n][j]);
          pv[j] = pp;
          l_r += pp;
        }
      }
      bf16x4 pk = { (bf16_t)pv[0], (bf16_t)pv[1], (bf16_t)pv[2], (bf16_t)pv[3] };
      const int slot = n * 2 + (lh >> 1);
      *(bf16x4*)(P + r15 * 64 + ((slot ^ (r15 & 7)) * 8) + (lh & 1) * 4) = pk;
    }

    bf16x8 pa0, pa1;
    {
      const int sw = r15 & 7;
      pa0 = *(const bf16x8*)(P + r15 * 64 + ((lh ^ sw) * 8));
      pa1 = *(const bf16x8*)(P + r15 * 64 + (((4 + lh) ^ sw) * 8));
    }
    __builtin_amdgcn_s_setprio(1);
#pragma unroll
    for (int n = 0; n < 4; ++n) {
      const int d = n * 16 + r15;
      const int sw = d & 7;
      bf16x8 vf0 = *(const bf16x8*)(Vb + d * 64 + ((lh ^ sw) * 8));
      bf16x8 vf1 = *(const bf16x8*)(Vb + d * 64 + (((4 + lh) ^ sw) * 8));
      o_acc[n] = __builtin_amdgcn_mfma_f32_16x16x32_bf16(vf0, pa0, o_acc[n], 0, 0, 0);
      o_acc[n] = __builtin_amdgcn_mfma_f32_16x16x32_bf16(vf1, pa1, o_acc[n], 0, 0, 0);
    }
    __builtin_amdgcn_s_setprio(0);

    __builtin_amdgcn_s_barrier();

    if (t == qtA) {
      float ls = l_r;
      ls += __shfl_xor(ls, 16, 64);
      ls += __shfl_xor(ls, 32, 64);
      const float invl = 1.f / ls;
      bf16_t* orow = Om + (size_t)(b * T_SEQ + qw + r15) * D_MODEL + h * 64;
#pragma unroll
      for (int n = 0; n < 4; ++n) {
        bf16x4 pk = { (bf16_t)(o_acc[n][0] * invl), (bf16_t)(o_acc[n][1] * invl),
                      (bf16_t)(o_acc[n][2] * invl), (bf16_t)(o_acc[n][3] * invl) };
        *(bf16x4*)(orow + n * 16 + lh * 4) = pk;
      }
      qw = qtB * 64 + w * 16;
      const bf16_t* qp = Qm + baseQ + (size_t)(qw + r15) * D_MODEL + lh * 8;
      qf[0] = *(const bf16x8*)(qp);
      qf[1] = *(const bf16x8*)(qp + 32);
      l_r = 0.f;
#pragma unroll
      for (int n = 0; n < 4; ++n) o_acc[n] = zero;
    }
  }

  float ls = l_r;
  ls += __shfl_xor(ls, 16, 64);
  ls += __shfl_xor(ls, 32, 64);
  const float invl = 1.f / ls;
  bf16_t* orow = Om + (size_t)(b * T_SEQ + qw + r15) * D_MODEL + h * 64;
#pragma unroll
  for (int n = 0; n < 4; ++n) {
    bf16x4 pk = { (bf16_t)(o_acc[n][0] * invl), (bf16_t)(o_acc[n][1] * invl),
                  (bf16_t)(o_acc[n][2] * invl), (bf16_t)(o_acc[n][3] * invl) };
    *(bf16x4*)(orow + n * 16 + lh * 4) = pk;
  }
}

// ---------------- host launch ----------------
extern "C" void kernel_launch(void* const* d_in, const int* in_sizes, int n_in,
                              void* d_out, int out_size, void* d_ws, size_t ws_size,
                              hipStream_t stream) {
  const float* x  = (const float*)d_in[0];
  const float* wq = (const float*)d_in[1];
  const float* bq = (const float*)d_in[2];
  const float* wk = (const float*)d_in[3];
  const float* bk = (const float*)d_in[4];
  const float* wv = (const float*)d_in[5];
  const float* bv = (const float*)d_in[6];
  const float* wo = (const float*)d_in[7];
  const float* bo = (const float*)d_in[8];

  char* ws = (char*)d_ws;
  const size_t MB = 1024 * 1024;
  bf16_t* xb  = (bf16_t*)(ws);
  bf16_t* wqb = (bf16_t*)(ws + 8 * MB);
  bf16_t* wkb = (bf16_t*)(ws + 10 * MB);
  bf16_t* wvb = (bf16_t*)(ws + 12 * MB);
  bf16_t* wob = (bf16_t*)(ws + 14 * MB);
  bf16_t* qb  = (bf16_t*)(ws + 16 * MB);
  bf16_t* kb  = (bf16_t*)(ws + 24 * MB);
  bf16_t* vtb = (bf16_t*)(ws + 32 * MB);  // V^T [B][1024][2048]
  bf16_t* ob  = (bf16_t*)(ws + 40 * MB);

  CastArgs ca;
  ca.src[0] = x;  ca.dst[0] = xb;
  ca.src[1] = wq; ca.dst[1] = wqb;
  ca.src[2] = wk; ca.dst[2] = wkb;
  ca.src[3] = wv; ca.dst[3] = wvb;
  ca.src[4] = wo; ca.dst[4] = wob;
  cast_all<<<8192, 256, 0, stream>>>(ca);

  QKVArgs qa;
  qa.A = xb;
  qa.W[0] = wqb; qa.W[1] = wkb; qa.W[2] = wvb;
  qa.bias[0] = bq; qa.bias[1] = bk; qa.bias[2] = bv;
  qa.out[0] = qb; qa.out[1] = kb; qa.out[2] = vtb;
  qkv_gemm<<<256, 512, 0, stream>>>(qa);

  flash_attn<<<512, 256, 0, stream>>>(qb, kb, vtb, ob);

  out_gemm<<<dim3(64, 8), 256, 0, stream>>>(ob, wob, bo, (float*)d_out);
}

// Round 9
// 97.378 us; speedup vs baseline: 1.2392x; 1.0405x over previous
//
#include <hip/hip_runtime.h>
#include <hip/hip_bf16.h>

typedef __bf16 bf16_t;
typedef __bf16 bf16x8 __attribute__((ext_vector_type(8)));
typedef __bf16 bf16x4 __attribute__((ext_vector_type(4)));
typedef float f32x4 __attribute__((ext_vector_type(4)));
typedef unsigned int u32;

#define D_MODEL 1024
#define T_SEQ   2048
#define N_HEADS 16

#define WAITVM(N) asm volatile("s_waitcnt vmcnt(" #N ")" ::: "memory")

__device__ __forceinline__ void gload_lds16(const void* g, void* l) {
  __builtin_amdgcn_global_load_lds((const __attribute__((address_space(1))) u32*)g,
                                   (__attribute__((address_space(3))) u32*)l, 16, 0, 0);
}

__device__ __forceinline__ float fast_exp2(float x) {
#if __has_builtin(__builtin_amdgcn_exp2f)
  return __builtin_amdgcn_exp2f(x);
#else
  return __expf(x * 0.69314718056f);
#endif
}

// ---------------- fused fp32->bf16 cast (x + 4 weights) ----------------
struct CastArgs { const float* src[5]; bf16_t* dst[5]; };

__global__ __launch_bounds__(256) void cast_all(CastArgs p) {
  unsigned i = (blockIdx.x * 256u + threadIdx.x) * 4u;
  int seg; unsigned off;
  if (i < 4194304u) { seg = 0; off = i; }
  else { unsigned r = i - 4194304u; seg = 1 + (int)(r >> 20); off = r & 1048575u; }
  const float4 v = *(const float4*)(p.src[seg] + off);
  bf16x4 o = { (bf16_t)v.x, (bf16_t)v.y, (bf16_t)v.z, (bf16_t)v.w };
  *(bf16x4*)(p.dst[seg] + off) = o;
}

#define QSCL 0.18033688011112042f   // 0.125 * log2(e)

// ============== fused QKV: 256x192 tile, BK=64, 4-phase, 512 thr ==============
struct QKVArgs {
  const bf16_t* A;
  const bf16_t* W[3];
  const float* bias[3];
  bf16_t* out[3];
};

__global__ __launch_bounds__(512, 2) void qkv_gemm(QKVArgs p) {
  __shared__ bf16_t lds[2 * 28672];   // [buf][A:16384 | B:12288]

  const int tid = threadIdx.x;
  const int l = tid & 63, wid = tid >> 6;
  const int lh = l >> 4, r15 = l & 15;

  const int lid = blockIdx.x;
  const int bx = lid >> 4, by = lid & 15;
  const int brow = bx * 256;
  const int gcol0 = by * 192;

  const int wr = (wid >> 2) * 128;
  const int wc = (wid & 3) * 48;
  const int wrc = (wr >> 4);
  const int wcc = (wc >> 4);
  const int sA = (lh ^ ((r15 >> 1) & 3)) * 8;
  const int roff = r15 * 32;

  const int srow = l >> 2;
  const int gs = ((l & 3) ^ ((l >> 3) & 3)) * 8;

  f32x4 acc[8][3];
  const f32x4 zero = {0.f, 0.f, 0.f, 0.f};
#pragma unroll
  for (int i = 0; i < 8; ++i)
#pragma unroll
    for (int j = 0; j < 3; ++j) acc[i][j] = zero;

  const bf16_t* A = p.A;

  auto stageA = [&](bf16_t* buf, int k0, int kh) {
#pragma unroll
    for (int i = 0; i < 2; ++i) {
      int c = wid * 2 + i;
      gload_lds16(A + (size_t)(brow + c * 16 + srow) * D_MODEL + k0 + kh * 32 + gs,
                  buf + kh * 8192 + c * 512);
    }
  };
  auto stageB = [&](bf16_t* buf, int k0) {
#pragma unroll
    for (int i = 0; i < 3; ++i) {
      int g = wid * 3 + i;
      int kh = g >= 12;
      int c = g - kh * 12;
      int gcol = gcol0 + c * 16 + srow;
      int z = gcol >> 10;
      const bf16_t* w = (z == 0) ? p.W[0] : ((z == 1) ? p.W[1] : p.W[2]);
      gload_lds16(w + (size_t)(gcol & 1023) * D_MODEL + k0 + kh * 32 + gs,
                  buf + 16384 + kh * 6144 + c * 512);
    }
  };

  stageA(lds, 0, 0);
  stageA(lds, 0, 1);
  stageB(lds, 0);
  WAITVM(0);
  __builtin_amdgcn_s_barrier();

  for (int t = 0; t < 16; ++t) {
    bf16_t* cur = lds + (t & 1) * 28672;
    bf16_t* nxt = lds + ((t + 1) & 1) * 28672;
    const int k1 = (t + 1) * 64;
    const bool more = (t < 15);

    bf16x8 bfr[3][2];
#pragma unroll
    for (int ph = 0; ph < 4; ++ph) {
      bf16x8 a[2][2];
#pragma unroll
      for (int jj = 0; jj < 2; ++jj)
#pragma unroll
        for (int kh = 0; kh < 2; ++kh)
          a[jj][kh] = *(const bf16x8*)(cur + kh * 8192 + (wrc + 2 * ph + jj) * 512 + roff + sA);
      if (ph == 0) {
#pragma unroll
        for (int ni = 0; ni < 3; ++ni)
#pragma unroll
          for (int kh = 0; kh < 2; ++kh)
            bfr[ni][kh] = *(const bf16x8*)(cur + 16384 + kh * 6144 + (wcc + ni) * 512 + roff + sA);
      }
      if (more) {
        if (ph == 0) stageA(nxt, k1, 0);
        else if (ph == 1) stageA(nxt, k1, 1);
        else if (ph == 2) stageB(nxt, k1);
      }
      __builtin_amdgcn_s_barrier();
      __builtin_amdgcn_s_setprio(1);
#pragma unroll
      for (int jj = 0; jj < 2; ++jj)
#pragma unroll
        for (int ni = 0; ni < 3; ++ni) {
          acc[2 * ph + jj][ni] = __builtin_amdgcn_mfma_f32_16x16x32_bf16(a[jj][0], bfr[ni][0], acc[2 * ph + jj][ni], 0, 0, 0);
          acc[2 * ph + jj][ni] = __builtin_amdgcn_mfma_f32_16x16x32_bf16(a[jj][1], bfr[ni][1], acc[2 * ph + jj][ni], 0, 0, 0);
        }
      __builtin_amdgcn_s_setprio(0);
      if (ph == 3 && more) WAITVM(0);
      __builtin_amdgcn_s_barrier();
    }
  }

#pragma unroll
  for (int ni = 0; ni < 3; ++ni) {
    const int col = gcol0 + wc + ni * 16 + r15;
    const int z = col >> 10;
    const int zc = col & 1023;
    const float* bias = (z == 0) ? p.bias[0] : ((z == 1) ? p.bias[1] : p.bias[2]);
    bf16_t* O = (z == 0) ? p.out[0] : ((z == 1) ? p.out[1] : p.out[2]);
    const float bz = bias[zc];
    if (z == 2) {
#pragma unroll
      for (int mi = 0; mi < 8; ++mi) {
        int row0 = brow + wr + mi * 16 + lh * 4;
        int bb = row0 >> 11, t0 = row0 & 2047;
        bf16x4 pk;
#pragma unroll
        for (int j = 0; j < 4; ++j) pk[j] = (bf16_t)(acc[mi][ni][j] + bz);
        *(bf16x4*)(O + (size_t)bb * (D_MODEL * T_SEQ) + (size_t)zc * T_SEQ + t0) = pk;
      }
    } else if (z == 0) {
#pragma unroll
      for (int mi = 0; mi < 8; ++mi) {
        int row0 = brow + wr + mi * 16 + lh * 4;
#pragma unroll
        for (int j = 0; j < 4; ++j)
          O[(size_t)(row0 + j) * D_MODEL + zc] = (bf16_t)((acc[mi][ni][j] + bz) * QSCL);
      }
    } else {
#pragma unroll
      for (int mi = 0; mi < 8; ++mi) {
        int row0 = brow + wr + mi * 16 + lh * 4;
#pragma unroll
        for (int j = 0; j < 4; ++j)
          O[(size_t)(row0 + j) * D_MODEL + zc] = (bf16_t)(acc[mi][ni][j] + bz);
      }
    }
  }
}

// ---------------- 64x128 GEMM (out projection) ----------------
__device__ __forceinline__ void stage_ab64(
    const bf16_t* __restrict__ A, const bf16_t* __restrict__ W,
    bf16_t* buf, int brow, int bcol, int k0, int w, int l) {
  const int srow = l >> 2;
  const int scol = ((l & 3) ^ ((l >> 3) & 3)) * 8;
#pragma unroll
  for (int i = 0; i < 3; ++i) {
    int ch = w * 3 + i;
    const bf16_t* src = (ch < 4)
      ? A + (size_t)(brow + ch * 16 + srow) * D_MODEL + k0 + scol
      : W + (size_t)(bcol + (ch - 4) * 16 + srow) * D_MODEL + k0 + scol;
    gload_lds16(src, buf + ch * 512);
  }
}

__device__ __forceinline__ void gemm_tile_64(
    const bf16_t* __restrict__ A, const bf16_t* __restrict__ W,
    bf16_t* bufs, int brow, int bcol, f32x4 acc[2][4])
{
  const int tid = threadIdx.x;
  const int l = tid & 63, w = tid >> 6;
  const int wr = (w >> 1) * 32, wc = (w & 1) * 64;
  const int lh = l >> 4, r15 = l & 15;
  const int NS = D_MODEL / 32;

  stage_ab64(A, W, bufs + 0 * 6144, brow, bcol, 0, w, l);
  stage_ab64(A, W, bufs + 1 * 6144, brow, bcol, 32, w, l);

  for (int t = 0; t < NS; ++t) {
    bf16_t* bb = bufs + (t % 3) * 6144;
    if (t + 2 < NS) {
      stage_ab64(A, W, bufs + ((t + 2) % 3) * 6144, brow, bcol, (t + 2) * 32, w, l);
      WAITVM(6);
    } else if (t + 1 < NS) {
      WAITVM(3);
    } else {
      WAITVM(0);
    }
    __builtin_amdgcn_s_barrier();

    bf16x8 af[2], bfr[4];
#pragma unroll
    for (int mi = 0; mi < 2; ++mi) {
      int rr = wr + mi * 16 + r15;
      int s = lh ^ ((rr >> 1) & 3);
      af[mi] = *(const bf16x8*)(bb + rr * 32 + s * 8);
    }
#pragma unroll
    for (int ni = 0; ni < 4; ++ni) {
      int rr = wc + ni * 16 + r15;
      int s = lh ^ ((rr >> 1) & 3);
      bfr[ni] = *(const bf16x8*)(bb + 2048 + rr * 32 + s * 8);
    }
    __builtin_amdgcn_s_setprio(1);
#pragma unroll
    for (int mi = 0; mi < 2; ++mi)
#pragma unroll
      for (int ni = 0; ni < 4; ++ni)
        acc[mi][ni] = __builtin_amdgcn_mfma_f32_16x16x32_bf16(af[mi], bfr[ni], acc[mi][ni], 0, 0, 0);
    __builtin_amdgcn_s_setprio(0);
    __builtin_amdgcn_s_barrier();
  }
}

__global__ __launch_bounds__(256) void out_gemm(
    const bf16_t* __restrict__ A, const bf16_t* __restrict__ W,
    const float* __restrict__ bias, float* __restrict__ O)
{
  __shared__ bf16_t bufs[3 * 6144];
  f32x4 acc[2][4];
  f32x4 zero = {0.f, 0.f, 0.f, 0.f};
#pragma unroll
  for (int i = 0; i < 2; ++i)
#pragma unroll
    for (int j = 0; j < 4; ++j) acc[i][j] = zero;

  const int brow = blockIdx.x * 64, bcol = blockIdx.y * 128;
  gemm_tile_64(A, W, bufs, brow, bcol, acc);

  const int tid = threadIdx.x, l = tid & 63, w = tid >> 6;
  const int wr = (w >> 1) * 32, wc = (w & 1) * 64, lh = l >> 4, r15 = l & 15;
#pragma unroll
  for (int ni = 0; ni < 4; ++ni) {
    int col = bcol + wc + ni * 16 + r15;
    float bz = bias[col];
#pragma unroll
    for (int mi = 0; mi < 2; ++mi) {
      int row0 = brow + wr + mi * 16 + lh * 4;
#pragma unroll
      for (int j = 0; j < 4; ++j)
        O[(size_t)(row0 + j) * D_MODEL + col] = acc[mi][ni][j] + bz;
    }
  }
}

// ---------------- causal flash attention: KVBLK = 128 ----------------
// Q (pre-scaled), K row-major [B*T][1024]; Vt [B][1024][2048]; O bf16 [B*T][1024]
// Folded-triangle: block does q-tiles {pair, 31-pair} (64 rows each) over
// 128-kv tiles = uniformly 17 tiles/block. 4 waves x 16 q-rows.
// K_lds [128][8 slots of 8, slot^(kv&7)]; Vt_lds [64][16 slots of 8, slot^(d&15)]
// P per-wave [16 q][stride 72], two 64-kv halves reuse the buffer.
__device__ __forceinline__ void stage_kv128(const bf16_t* Kg, const bf16_t* Vg,
                                            bf16_t* Kd, bf16_t* Vd, int kv0, int w, int l) {
#pragma unroll
  for (int i = 0; i < 4; ++i) {
    int c = w * 4 + i;
    int row = c * 8 + (l >> 3);
    int gcol = ((l & 7) ^ ((l >> 3) & 7)) * 8;
    gload_lds16(Kg + (size_t)(kv0 + row) * D_MODEL + gcol, Kd + c * 512);
  }
#pragma unroll
  for (int i = 0; i < 4; ++i) {
    int c = w * 4 + i;
    int drow = c * 4 + (l >> 4);
    int gkv = ((l & 15) ^ (drow & 15)) * 8;
    gload_lds16(Vg + (size_t)drow * T_SEQ + kv0 + gkv, Vd + c * 512);
  }
}

__global__ __launch_bounds__(256) void flash_attn(
    const bf16_t* __restrict__ Qm, const bf16_t* __restrict__ Km,
    const bf16_t* __restrict__ Vtg, bf16_t* __restrict__ Om)
{
  __shared__ bf16_t Kls[2][128 * 64];
  __shared__ bf16_t Vls[2][64 * 128];
  __shared__ bf16_t Pls[4][16 * 72];

  const int tid = threadIdx.x, l = tid & 63, w = tid >> 6;
  const int lh = l >> 4, r15 = l & 15;

  const int lid = blockIdx.x;
  const int xcd = lid & 7;
  const int idx = lid >> 3;
  const int pair = idx & 15;
  const int bh = xcd + 8 * (idx >> 4);
  const int b = bh >> 4, h = bh & 15;
  const int qtA = pair, qtB = 31 - pair;
  const int nA = (qtA >> 1) + 1;
  const int NT = 17;

  const size_t baseQ = (size_t)b * T_SEQ * D_MODEL + h * 64;
  const size_t baseVt = (size_t)b * (D_MODEL * T_SEQ) + (size_t)(h * 64) * T_SEQ;
  const bf16_t* Kg = Km + baseQ;
  const bf16_t* Vg = Vtg + baseVt;

  int qw = qtA * 64 + w * 16;

  bf16x8 qf[2];
  {
    const bf16_t* qp = Qm + baseQ + (size_t)(qw + r15) * D_MODEL + lh * 8;
    qf[0] = *(const bf16x8*)(qp);
    qf[1] = *(const bf16x8*)(qp + 32);
  }

  float l_r = 0.f;
  f32x4 o_acc[4];
  const f32x4 zero = {0.f, 0.f, 0.f, 0.f};
#pragma unroll
  for (int n = 0; n < 4; ++n) o_acc[n] = zero;

  bf16_t* P = &Pls[w][0];

  stage_kv128(Kg, Vg, Kls[0], Vls[0], 0, w, l);

  for (int t = 0; t < NT; ++t) {
    const int buf = t & 1;
    if (t + 1 < NT) {
      const int nt = t + 1;
      const int nkv0 = (nt < nA) ? nt * 128 : (nt - nA) * 128;
      stage_kv128(Kg, Vg, Kls[buf ^ 1], Vls[buf ^ 1], nkv0, w, l);
      WAITVM(8);
    } else {
      WAITVM(0);
    }
    __builtin_amdgcn_s_barrier();

    const int kv0 = (t < nA) ? t * 128 : (t - nA) * 128;
    const int qt_cur = (t < nA) ? qtA : qtB;
    const bool diag = (t == nA - 1) || (t == NT - 1);
    const bool skip2 = diag && ((qt_cur & 1) == 0);
    const bf16_t* Kb = Kls[buf];
    const bf16_t* Vb = Vls[buf];
    const int qrow = qw + r15;

    f32x4 sf[8];
    auto qk_n = [&](int n) {
      const int kvc = n * 16 + r15;
      const int sw = kvc & 7;
      bf16x8 kf0 = *(const bf16x8*)(Kb + kvc * 64 + ((lh ^ sw) * 8));
      bf16x8 kf1 = *(const bf16x8*)(Kb + kvc * 64 + (((4 + lh) ^ sw) * 8));
      f32x4 a = zero;
      a = __builtin_amdgcn_mfma_f32_16x16x32_bf16(kf0, qf[0], a, 0, 0, 0);
      a = __builtin_amdgcn_mfma_f32_16x16x32_bf16(kf1, qf[1], a, 0, 0, 0);
      sf[n] = a;
    };
    auto sm_half = [&](int hh, bool dm) {
#pragma unroll
      for (int n2 = 0; n2 < 4; ++n2) {
        const int n = hh * 4 + n2;
        float pv[4];
#pragma unroll
        for (int j = 0; j < 4; ++j) {
          float pp = fast_exp2(sf[n][j]);
          if (dm) {
            const int kvcol = kv0 + hh * 64 + n2 * 16 + lh * 4 + j;
            if (kvcol > qrow) pp = 0.f;
          }
          pv[j] = pp;
          l_r += pp;
        }
        bf16x4 pk = { (bf16_t)pv[0], (bf16_t)pv[1], (bf16_t)pv[2], (bf16_t)pv[3] };
        *(bf16x4*)(P + r15 * 72 + (n2 * 2 + (lh >> 1)) * 8 + (lh & 1) * 4) = pk;
      }
    };
    auto pv_half = [&](int hh) {
      bf16x8 pa0 = *(const bf16x8*)(P + r15 * 72 + lh * 8);
      bf16x8 pa1 = *(const bf16x8*)(P + r15 * 72 + (4 + lh) * 8);
      __builtin_amdgcn_s_setprio(1);
#pragma unroll
      for (int nD = 0; nD < 4; ++nD) {
        const int d = nD * 16 + r15;
        const int b0 = (hh * 8 + lh) ^ r15;
        const int b1 = (hh * 8 + 4 + lh) ^ r15;
        bf16x8 vf0 = *(const bf16x8*)(Vb + d * 128 + b0 * 8);
        bf16x8 vf1 = *(const bf16x8*)(Vb + d * 128 + b1 * 8);
        o_acc[nD] = __builtin_amdgcn_mfma_f32_16x16x32_bf16(vf0, pa0, o_acc[nD], 0, 0, 0);
        o_acc[nD] = __builtin_amdgcn_mfma_f32_16x16x32_bf16(vf1, pa1, o_acc[nD], 0, 0, 0);
      }
      __builtin_amdgcn_s_setprio(0);
    };

    __builtin_amdgcn_s_setprio(1);
#pragma unroll
    for (int n = 0; n < 4; ++n) qk_n(n);
    __builtin_amdgcn_s_setprio(0);
    if (!skip2) {
      __builtin_amdgcn_s_setprio(1);
#pragma unroll
      for (int n = 4; n < 8; ++n) qk_n(n);
      __builtin_amdgcn_s_setprio(0);
    }

    if (diag) {
      sm_half(0, true);
      pv_half(0);
      if (!skip2) { sm_half(1, true); pv_half(1); }
    } else {
      sm_half(0, false);
      pv_half(0);
      sm_half(1, false);
      pv_half(1);
    }

    __builtin_amdgcn_s_barrier();

    if (t == nA - 1) {
      float ls = l_r;
      ls += __shfl_xor(ls, 16, 64);
      ls += __shfl_xor(ls, 32, 64);
      const float invl = 1.f / ls;
      bf16_t* orow = Om + (size_t)(b * T_SEQ + qw + r15) * D_MODEL + h * 64;
#pragma unroll
      for (int n = 0; n < 4; ++n) {
        bf16x4 pk = { (bf16_t)(o_acc[n][0] * invl), (bf16_t)(o_acc[n][1] * invl),
                      (bf16_t)(o_acc[n][2] * invl), (bf16_t)(o_acc[n][3] * invl) };
        *(bf16x4*)(orow + n * 16 + lh * 4) = pk;
      }
      qw = qtB * 64 + w * 16;
      const bf16_t* qp = Qm + baseQ + (size_t)(qw + r15) * D_MODEL + lh * 8;
      qf[0] = *(const bf16x8*)(qp);
      qf[1] = *(const bf16x8*)(qp + 32);
      l_r = 0.f;
#pragma unroll
      for (int n = 0; n < 4; ++n) o_acc[n] = zero;
    }
  }

  float ls = l_r;
  ls += __shfl_xor(ls, 16, 64);
  ls += __shfl_xor(ls, 32, 64);
  const float invl = 1.f / ls;
  bf16_t* orow = Om + (size_t)(b * T_SEQ + qw + r15) * D_MODEL + h * 64;
#pragma unroll
  for (int n = 0; n < 4; ++n) {
    bf16x4 pk = { (bf16_t)(o_acc[n][0] * invl), (bf16_t)(o_acc[n][1] * invl),
                  (bf16_t)(o_acc[n][2] * invl), (bf16_t)(o_acc[n][3] * invl) };
    *(bf16x4*)(orow + n * 16 + lh * 4) = pk;
  }
}

// ---------------- host launch ----------------
extern "C" void kernel_launch(void* const* d_in, const int* in_sizes, int n_in,
                              void* d_out, int out_size, void* d_ws, size_t ws_size,
                              hipStream_t stream) {
  const float* x  = (const float*)d_in[0];
  const float* wq = (const float*)d_in[1];
  const float* bq = (const float*)d_in[2];
  const float* wk = (const float*)d_in[3];
  const float* bk = (const float*)d_in[4];
  const float* wv = (const float*)d_in[5];
  const float* bv = (const float*)d_in[6];
  const float* wo = (const float*)d_in[7];
  const float* bo = (const float*)d_in[8];

  char* ws = (char*)d_ws;
  const size_t MB = 1024 * 1024;
  bf16_t* xb  = (bf16_t*)(ws);
  bf16_t* wqb = (bf16_t*)(ws + 8 * MB);
  bf16_t* wkb = (bf16_t*)(ws + 10 * MB);
  bf16_t* wvb = (bf16_t*)(ws + 12 * MB);
  bf16_t* wob = (bf16_t*)(ws + 14 * MB);
  bf16_t* qb  = (bf16_t*)(ws + 16 * MB);
  bf16_t* kb  = (bf16_t*)(ws + 24 * MB);
  bf16_t* vtb = (bf16_t*)(ws + 32 * MB);  // V^T [B][1024][2048]
  bf16_t* ob  = (bf16_t*)(ws + 40 * MB);

  CastArgs ca;
  ca.src[0] = x;  ca.dst[0] = xb;
  ca.src[1] = wq; ca.dst[1] = wqb;
  ca.src[2] = wk; ca.dst[2] = wkb;
  ca.src[3] = wv; ca.dst[3] = wvb;
  ca.src[4] = wo; ca.dst[4] = wob;
  cast_all<<<8192, 256, 0, stream>>>(ca);

  QKVArgs qa;
  qa.A = xb;
  qa.W[0] = wqb; qa.W[1] = wkb; qa.W[2] = wvb;
  qa.bias[0] = bq; qa.bias[1] = bk; qa.bias[2] = bv;
  qa.out[0] = qb; qa.out[1] = kb; qa.out[2] = vtb;
  qkv_gemm<<<256, 512, 0, stream>>>(qa);

  flash_attn<<<512, 256, 0, stream>>>(qb, kb, vtb, ob);

  out_gemm<<<dim3(64, 8), 256, 0, stream>>>(ob, wob, bo, (float*)d_out);
}

// Round 10
// 94.699 us; speedup vs baseline: 1.2743x; 1.0283x over previous
//
#include <hip/hip_runtime.h>
#include <hip/hip_bf16.h>

typedef __bf16 bf16_t;
typedef __bf16 bf16x8 __attribute__((ext_vector_type(8)));
typedef __bf16 bf16x4 __attribute__((ext_vector_type(4)));
typedef float f32x4 __attribute__((ext_vector_type(4)));
typedef unsigned int u32;

#define D_MODEL 1024
#define T_SEQ   2048
#define N_HEADS 16

#define WAITVM(N) asm volatile("s_waitcnt vmcnt(" #N ")" ::: "memory")

__device__ __forceinline__ void gload_lds16(const void* g, void* l) {
  __builtin_amdgcn_global_load_lds((const __attribute__((address_space(1))) u32*)g,
                                   (__attribute__((address_space(3))) u32*)l, 16, 0, 0);
}

__device__ __forceinline__ float fast_exp2(float x) {
#if __has_builtin(__builtin_amdgcn_exp2f)
  return __builtin_amdgcn_exp2f(x);
#else
  return __expf(x * 0.69314718056f);
#endif
}

// ---------------- fused fp32->bf16 cast (x + 4 weights) ----------------
struct CastArgs { const float* src[5]; bf16_t* dst[5]; };

__global__ __launch_bounds__(256) void cast_all(CastArgs p) {
  unsigned i = (blockIdx.x * 256u + threadIdx.x) * 4u;
  int seg; unsigned off;
  if (i < 4194304u) { seg = 0; off = i; }
  else { unsigned r = i - 4194304u; seg = 1 + (int)(r >> 20); off = r & 1048575u; }
  const float4 v = *(const float4*)(p.src[seg] + off);
  bf16x4 o = { (bf16_t)v.x, (bf16_t)v.y, (bf16_t)v.z, (bf16_t)v.w };
  *(bf16x4*)(p.dst[seg] + off) = o;
}

#define QSCL 0.18033688011112042f   // 0.125 * log2(e)

// ============== fused QKV: 256x192 tile, BK=64, 4-phase, 512 thr ==============
struct QKVArgs {
  const bf16_t* A;
  const bf16_t* W[3];
  const float* bias[3];
  bf16_t* out[3];
};

__global__ __launch_bounds__(512, 2) void qkv_gemm(QKVArgs p) {
  __shared__ bf16_t lds[2 * 28672];   // [buf][A:16384 | B:12288]

  const int tid = threadIdx.x;
  const int l = tid & 63, wid = tid >> 6;
  const int lh = l >> 4, r15 = l & 15;

  const int lid = blockIdx.x;
  const int bx = lid >> 4, by = lid & 15;
  const int brow = bx * 256;
  const int gcol0 = by * 192;

  const int wr = (wid >> 2) * 128;
  const int wc = (wid & 3) * 48;
  const int wrc = (wr >> 4);
  const int wcc = (wc >> 4);
  const int sA = (lh ^ ((r15 >> 1) & 3)) * 8;
  const int roff = r15 * 32;

  const int srow = l >> 2;
  const int gs = ((l & 3) ^ ((l >> 3) & 3)) * 8;

  f32x4 acc[8][3];
  const f32x4 zero = {0.f, 0.f, 0.f, 0.f};
#pragma unroll
  for (int i = 0; i < 8; ++i)
#pragma unroll
    for (int j = 0; j < 3; ++j) acc[i][j] = zero;

  const bf16_t* A = p.A;

  auto stageA = [&](bf16_t* buf, int k0, int kh) {
#pragma unroll
    for (int i = 0; i < 2; ++i) {
      int c = wid * 2 + i;
      gload_lds16(A + (size_t)(brow + c * 16 + srow) * D_MODEL + k0 + kh * 32 + gs,
                  buf + kh * 8192 + c * 512);
    }
  };
  auto stageB = [&](bf16_t* buf, int k0) {
#pragma unroll
    for (int i = 0; i < 3; ++i) {
      int g = wid * 3 + i;
      int kh = g >= 12;
      int c = g - kh * 12;
      int gcol = gcol0 + c * 16 + srow;
      int z = gcol >> 10;
      const bf16_t* w = (z == 0) ? p.W[0] : ((z == 1) ? p.W[1] : p.W[2]);
      gload_lds16(w + (size_t)(gcol & 1023) * D_MODEL + k0 + kh * 32 + gs,
                  buf + 16384 + kh * 6144 + c * 512);
    }
  };

  stageA(lds, 0, 0);
  stageA(lds, 0, 1);
  stageB(lds, 0);
  WAITVM(0);
  __builtin_amdgcn_s_barrier();

  for (int t = 0; t < 16; ++t) {
    bf16_t* cur = lds + (t & 1) * 28672;
    bf16_t* nxt = lds + ((t + 1) & 1) * 28672;
    const int k1 = (t + 1) * 64;
    const bool more = (t < 15);

    bf16x8 bfr[3][2];
#pragma unroll
    for (int ph = 0; ph < 4; ++ph) {
      bf16x8 a[2][2];
#pragma unroll
      for (int jj = 0; jj < 2; ++jj)
#pragma unroll
        for (int kh = 0; kh < 2; ++kh)
          a[jj][kh] = *(const bf16x8*)(cur + kh * 8192 + (wrc + 2 * ph + jj) * 512 + roff + sA);
      if (ph == 0) {
#pragma unroll
        for (int ni = 0; ni < 3; ++ni)
#pragma unroll
          for (int kh = 0; kh < 2; ++kh)
            bfr[ni][kh] = *(const bf16x8*)(cur + 16384 + kh * 6144 + (wcc + ni) * 512 + roff + sA);
      }
      if (more) {
        if (ph == 0) stageA(nxt, k1, 0);
        else if (ph == 1) stageA(nxt, k1, 1);
        else if (ph == 2) stageB(nxt, k1);
      }
      __builtin_amdgcn_s_barrier();
      __builtin_amdgcn_s_setprio(1);
#pragma unroll
      for (int jj = 0; jj < 2; ++jj)
#pragma unroll
        for (int ni = 0; ni < 3; ++ni) {
          acc[2 * ph + jj][ni] = __builtin_amdgcn_mfma_f32_16x16x32_bf16(a[jj][0], bfr[ni][0], acc[2 * ph + jj][ni], 0, 0, 0);
          acc[2 * ph + jj][ni] = __builtin_amdgcn_mfma_f32_16x16x32_bf16(a[jj][1], bfr[ni][1], acc[2 * ph + jj][ni], 0, 0, 0);
        }
      __builtin_amdgcn_s_setprio(0);
      if (ph == 3 && more) WAITVM(0);
      __builtin_amdgcn_s_barrier();
    }
  }

#pragma unroll
  for (int ni = 0; ni < 3; ++ni) {
    const int col = gcol0 + wc + ni * 16 + r15;
    const int z = col >> 10;
    const int zc = col & 1023;
    const float* bias = (z == 0) ? p.bias[0] : ((z == 1) ? p.bias[1] : p.bias[2]);
    bf16_t* O = (z == 0) ? p.out[0] : ((z == 1) ? p.out[1] : p.out[2]);
    const float bz = bias[zc];
    if (z == 2) {
#pragma unroll
      for (int mi = 0; mi < 8; ++mi) {
        int row0 = brow + wr + mi * 16 + lh * 4;
        int bb = row0 >> 11, t0 = row0 & 2047;
        bf16x4 pk;
#pragma unroll
        for (int j = 0; j < 4; ++j) pk[j] = (bf16_t)(acc[mi][ni][j] + bz);
        *(bf16x4*)(O + (size_t)bb * (D_MODEL * T_SEQ) + (size_t)zc * T_SEQ + t0) = pk;
      }
    } else if (z == 0) {
#pragma unroll
      for (int mi = 0; mi < 8; ++mi) {
        int row0 = brow + wr + mi * 16 + lh * 4;
#pragma unroll
        for (int j = 0; j < 4; ++j)
          O[(size_t)(row0 + j) * D_MODEL + zc] = (bf16_t)((acc[mi][ni][j] + bz) * QSCL);
      }
    } else {
#pragma unroll
      for (int mi = 0; mi < 8; ++mi) {
        int row0 = brow + wr + mi * 16 + lh * 4;
#pragma unroll
        for (int j = 0; j < 4; ++j)
          O[(size_t)(row0 + j) * D_MODEL + zc] = (bf16_t)(acc[mi][ni][j] + bz);
      }
    }
  }
}

// ---------------- 64x128 GEMM (out projection) ----------------
__device__ __forceinline__ void stage_ab64(
    const bf16_t* __restrict__ A, const bf16_t* __restrict__ W,
    bf16_t* buf, int brow, int bcol, int k0, int w, int l) {
  const int srow = l >> 2;
  const int scol = ((l & 3) ^ ((l >> 3) & 3)) * 8;
#pragma unroll
  for (int i = 0; i < 3; ++i) {
    int ch = w * 3 + i;
    const bf16_t* src = (ch < 4)
      ? A + (size_t)(brow + ch * 16 + srow) * D_MODEL + k0 + scol
      : W + (size_t)(bcol + (ch - 4) * 16 + srow) * D_MODEL + k0 + scol;
    gload_lds16(src, buf + ch * 512);
  }
}

__device__ __forceinline__ void gemm_tile_64(
    const bf16_t* __restrict__ A, const bf16_t* __restrict__ W,
    bf16_t* bufs, int brow, int bcol, f32x4 acc[2][4])
{
  const int tid = threadIdx.x;
  const int l = tid & 63, w = tid >> 6;
  const int wr = (w >> 1) * 32, wc = (w & 1) * 64;
  const int lh = l >> 4, r15 = l & 15;
  const int NS = D_MODEL / 32;

  stage_ab64(A, W, bufs + 0 * 6144, brow, bcol, 0, w, l);
  stage_ab64(A, W, bufs + 1 * 6144, brow, bcol, 32, w, l);

  for (int t = 0; t < NS; ++t) {
    bf16_t* bb = bufs + (t % 3) * 6144;
    if (t + 2 < NS) {
      stage_ab64(A, W, bufs + ((t + 2) % 3) * 6144, brow, bcol, (t + 2) * 32, w, l);
      WAITVM(6);
    } else if (t + 1 < NS) {
      WAITVM(3);
    } else {
      WAITVM(0);
    }
    __builtin_amdgcn_s_barrier();

    bf16x8 af[2], bfr[4];
#pragma unroll
    for (int mi = 0; mi < 2; ++mi) {
      int rr = wr + mi * 16 + r15;
      int s = lh ^ ((rr >> 1) & 3);
      af[mi] = *(const bf16x8*)(bb + rr * 32 + s * 8);
    }
#pragma unroll
    for (int ni = 0; ni < 4; ++ni) {
      int rr = wc + ni * 16 + r15;
      int s = lh ^ ((rr >> 1) & 3);
      bfr[ni] = *(const bf16x8*)(bb + 2048 + rr * 32 + s * 8);
    }
    __builtin_amdgcn_s_setprio(1);
#pragma unroll
    for (int mi = 0; mi < 2; ++mi)
#pragma unroll
      for (int ni = 0; ni < 4; ++ni)
        acc[mi][ni] = __builtin_amdgcn_mfma_f32_16x16x32_bf16(af[mi], bfr[ni], acc[mi][ni], 0, 0, 0);
    __builtin_amdgcn_s_setprio(0);
    __builtin_amdgcn_s_barrier();
  }
}

__global__ __launch_bounds__(256) void out_gemm(
    const bf16_t* __restrict__ A, const bf16_t* __restrict__ W,
    const float* __restrict__ bias, float* __restrict__ O)
{
  __shared__ bf16_t bufs[3 * 6144];
  f32x4 acc[2][4];
  f32x4 zero = {0.f, 0.f, 0.f, 0.f};
#pragma unroll
  for (int i = 0; i < 2; ++i)
#pragma unroll
    for (int j = 0; j < 4; ++j) acc[i][j] = zero;

  const int brow = blockIdx.x * 64, bcol = blockIdx.y * 128;
  gemm_tile_64(A, W, bufs, brow, bcol, acc);

  const int tid = threadIdx.x, l = tid & 63, w = tid >> 6;
  const int wr = (w >> 1) * 32, wc = (w & 1) * 64, lh = l >> 4, r15 = l & 15;
#pragma unroll
  for (int ni = 0; ni < 4; ++ni) {
    int col = bcol + wc + ni * 16 + r15;
    float bz = bias[col];
#pragma unroll
    for (int mi = 0; mi < 2; ++mi) {
      int row0 = brow + wr + mi * 16 + lh * 4;
#pragma unroll
      for (int j = 0; j < 4; ++j)
        O[(size_t)(row0 + j) * D_MODEL + col] = acc[mi][ni][j] + bz;
    }
  }
}

// ---------------- causal flash attention: unfolded, KVBLK=128 ----------------
// 1024 blocks: lid -> qt = 31-(lid>>5) (LPT order), bh = lid&31 (head on fixed XCD).
// Each block: one 64-row q-tile, (qt>>1)+1 kv-tiles of 128.
// K single-buffer (restage after post-QK barrier), V single-buffer (restage after
// post-PV barrier, lands during next QK/softmax), P double-buffered per wave.
// LDS 50KB -> 3 blocks/CU resident.
__device__ __forceinline__ void stage_k128(const bf16_t* Kg, bf16_t* Kd, int kv0, int w, int l) {
#pragma unroll
  for (int i = 0; i < 4; ++i) {
    int c = w * 4 + i;
    int row = c * 8 + (l >> 3);
    int gcol = ((l & 7) ^ ((l >> 3) & 7)) * 8;
    gload_lds16(Kg + (size_t)(kv0 + row) * D_MODEL + gcol, Kd + c * 512);
  }
}
__device__ __forceinline__ void stage_v128(const bf16_t* Vg, bf16_t* Vd, int kv0, int w, int l) {
#pragma unroll
  for (int i = 0; i < 4; ++i) {
    int c = w * 4 + i;
    int drow = c * 4 + (l >> 4);
    int gkv = ((l & 15) ^ (drow & 15)) * 8;
    gload_lds16(Vg + (size_t)drow * T_SEQ + kv0 + gkv, Vd + c * 512);
  }
}

__global__ __launch_bounds__(256) void flash_attn(
    const bf16_t* __restrict__ Qm, const bf16_t* __restrict__ Km,
    const bf16_t* __restrict__ Vtg, bf16_t* __restrict__ Om)
{
  __shared__ bf16_t Kls[128 * 64];
  __shared__ bf16_t Vls[64 * 128];
  __shared__ bf16_t Pls[4][2][16 * 72];

  const int tid = threadIdx.x, l = tid & 63, w = tid >> 6;
  const int lh = l >> 4, r15 = l & 15;

  const int lid = blockIdx.x;
  const int qt = 31 - (lid >> 5);       // big q-tiles dispatch first (LPT)
  const int bh = lid & 31;              // bh%8 == lid%8 -> head pinned to one XCD
  const int b = bh >> 4, h = bh & 15;
  const int nT = (qt >> 1) + 1;

  const size_t baseQ = (size_t)b * T_SEQ * D_MODEL + h * 64;
  const size_t baseVt = (size_t)b * (D_MODEL * T_SEQ) + (size_t)(h * 64) * T_SEQ;
  const bf16_t* Kg = Km + baseQ;
  const bf16_t* Vg = Vtg + baseVt;

  const int qw = qt * 64 + w * 16;
  const int qrow = qw + r15;

  bf16x8 qf[2];
  {
    const bf16_t* qp = Qm + baseQ + (size_t)(qw + r15) * D_MODEL + lh * 8;
    qf[0] = *(const bf16x8*)(qp);
    qf[1] = *(const bf16x8*)(qp + 32);
  }

  float l_r = 0.f;
  f32x4 o_acc[4];
  const f32x4 zero = {0.f, 0.f, 0.f, 0.f};
#pragma unroll
  for (int n = 0; n < 4; ++n) o_acc[n] = zero;

  bf16_t* PA = &Pls[w][0][0];
  bf16_t* PB = &Pls[w][1][0];

  stage_k128(Kg, Kls, 0, w, l);
  stage_v128(Vg, Vls, 0, w, l);
  WAITVM(0);
  __builtin_amdgcn_s_barrier();

  for (int t = 0; t < nT; ++t) {
    const int kv0 = t * 128;
    const bool more = (t + 1 < nT);
    const bool diag = (t == nT - 1);
    const bool skip2 = diag && ((qt & 1) == 0);

    // ---- S^T = K Q^T ----
    f32x4 sf[8];
    auto qk_n = [&](int n) {
      const int kvc = n * 16 + r15;
      const int sw = kvc & 7;
      bf16x8 kf0 = *(const bf16x8*)(Kls + kvc * 64 + ((lh ^ sw) * 8));
      bf16x8 kf1 = *(const bf16x8*)(Kls + kvc * 64 + (((4 + lh) ^ sw) * 8));
      f32x4 a = zero;
      a = __builtin_amdgcn_mfma_f32_16x16x32_bf16(kf0, qf[0], a, 0, 0, 0);
      a = __builtin_amdgcn_mfma_f32_16x16x32_bf16(kf1, qf[1], a, 0, 0, 0);
      sf[n] = a;
    };
    __builtin_amdgcn_s_setprio(1);
#pragma unroll
    for (int n = 0; n < 4; ++n) qk_n(n);
    __builtin_amdgcn_s_setprio(0);
    if (!skip2) {
      __builtin_amdgcn_s_setprio(1);
#pragma unroll
      for (int n = 4; n < 8; ++n) qk_n(n);
      __builtin_amdgcn_s_setprio(0);
    }

    __builtin_amdgcn_s_barrier();          // all waves done reading K
    if (more) stage_k128(Kg, Kls, kv0 + 128, w, l);

    // ---- softmax halves -> P dbuf (per-wave, no barrier needed) ----
    auto sm_half = [&](int hh, bf16_t* P, bool dm) {
#pragma unroll
      for (int n2 = 0; n2 < 4; ++n2) {
        const int n = hh * 4 + n2;
        float pv[4];
#pragma unroll
        for (int j = 0; j < 4; ++j) {
          float pp = fast_exp2(sf[n][j]);
          if (dm) {
            const int kvcol = kv0 + hh * 64 + n2 * 16 + lh * 4 + j;
            if (kvcol > qrow) pp = 0.f;
          }
          pv[j] = pp;
          l_r += pp;
        }
        bf16x4 pk = { (bf16_t)pv[0], (bf16_t)pv[1], (bf16_t)pv[2], (bf16_t)pv[3] };
        *(bf16x4*)(P + r15 * 72 + (n2 * 2 + (lh >> 1)) * 8 + (lh & 1) * 4) = pk;
      }
    };
    sm_half(0, PA, diag);
    if (!skip2) sm_half(1, PB, diag);

    if (more) WAITVM(4); else WAITVM(0);   // V(t) landed (oldest); K(t+1) may fly

    // ---- O += P V ----
    auto pv_half = [&](int hh, const bf16_t* P) {
      bf16x8 pa0 = *(const bf16x8*)(P + r15 * 72 + lh * 8);
      bf16x8 pa1 = *(const bf16x8*)(P + r15 * 72 + (4 + lh) * 8);
      __builtin_amdgcn_s_setprio(1);
#pragma unroll
      for (int nD = 0; nD < 4; ++nD) {
        const int d = nD * 16 + r15;
        const int b0 = (hh * 8 + lh) ^ r15;
        const int b1 = (hh * 8 + 4 + lh) ^ r15;
        bf16x8 vf0 = *(const bf16x8*)(Vls + d * 128 + b0 * 8);
        bf16x8 vf1 = *(const bf16x8*)(Vls + d * 128 + b1 * 8);
        o_acc[nD] = __builtin_amdgcn_mfma_f32_16x16x32_bf16(vf0, pa0, o_acc[nD], 0, 0, 0);
        o_acc[nD] = __builtin_amdgcn_mfma_f32_16x16x32_bf16(vf1, pa1, o_acc[nD], 0, 0, 0);
      }
      __builtin_amdgcn_s_setprio(0);
    };
    pv_half(0, PA);
    if (!skip2) pv_half(1, PB);

    __builtin_amdgcn_s_barrier();          // all waves done reading V(t)
    if (more) {
      stage_v128(Vg, Vls, kv0 + 128, w, l);
      WAITVM(4);                           // K(t+1) landed; V(t+1) stays in flight
    }
  }

  // ---- epilogue ----
  float ls = l_r;
  ls += __shfl_xor(ls, 16, 64);
  ls += __shfl_xor(ls, 32, 64);
  const float invl = 1.f / ls;
  bf16_t* orow = Om + (size_t)(b * T_SEQ + qw + r15) * D_MODEL + h * 64;
#pragma unroll
  for (int n = 0; n < 4; ++n) {
    bf16x4 pk = { (bf16_t)(o_acc[n][0] * invl), (bf16_t)(o_acc[n][1] * invl),
                  (bf16_t)(o_acc[n][2] * invl), (bf16_t)(o_acc[n][3] * invl) };
    *(bf16x4*)(orow + n * 16 + lh * 4) = pk;
  }
}

// ---------------- host launch ----------------
extern "C" void kernel_launch(void* const* d_in, const int* in_sizes, int n_in,
                              void* d_out, int out_size, void* d_ws, size_t ws_size,
                              hipStream_t stream) {
  const float* x  = (const float*)d_in[0];
  const float* wq = (const float*)d_in[1];
  const float* bq = (const float*)d_in[2];
  const float* wk = (const float*)d_in[3];
  const float* bk = (const float*)d_in[4];
  const float* wv = (const float*)d_in[5];
  const float* bv = (const float*)d_in[6];
  const float* wo = (const float*)d_in[7];
  const float* bo = (const float*)d_in[8];

  char* ws = (char*)d_ws;
  const size_t MB = 1024 * 1024;
  bf16_t* xb  = (bf16_t*)(ws);
  bf16_t* wqb = (bf16_t*)(ws + 8 * MB);
  bf16_t* wkb = (bf16_t*)(ws + 10 * MB);
  bf16_t* wvb = (bf16_t*)(ws + 12 * MB);
  bf16_t* wob = (bf16_t*)(ws + 14 * MB);
  bf16_t* qb  = (bf16_t*)(ws + 16 * MB);
  bf16_t* kb  = (bf16_t*)(ws + 24 * MB);
  bf16_t* vtb = (bf16_t*)(ws + 32 * MB);  // V^T [B][1024][2048]
  bf16_t* ob  = (bf16_t*)(ws + 40 * MB);

  CastArgs ca;
  ca.src[0] = x;  ca.dst[0] = xb;
  ca.src[1] = wq; ca.dst[1] = wqb;
  ca.src[2] = wk; ca.dst[2] = wkb;
  ca.src[3] = wv; ca.dst[3] = wvb;
  ca.src[4] = wo; ca.dst[4] = wob;
  cast_all<<<8192, 256, 0, stream>>>(ca);

  QKVArgs qa;
  qa.A = xb;
  qa.W[0] = wqb; qa.W[1] = wkb; qa.W[2] = wvb;
  qa.bias[0] = bq; qa.bias[1] = bk; qa.bias[2] = bv;
  qa.out[0] = qb; qa.out[1] = kb; qa.out[2] = vtb;
  qkv_gemm<<<256, 512, 0, stream>>>(qa);

  flash_attn<<<1024, 256, 0, stream>>>(qb, kb, vtb, ob);

  out_gemm<<<dim3(64, 8), 256, 0, stream>>>(ob, wob, bo, (float*)d_out);
}